// Round 8
// baseline (465.211 us; speedup 1.0000x reference)
//
#include <hip/hip_runtime.h>
#include <hip/hip_bf16.h>

// Problem dims
#define BB 2
#define TT 16
#define DD 64
#define HH 64
#define WW 64
#define NPIX 131072

// ESTABLISHED (R0-R9, R9 PASSED @ 6288us; prev session best 1320us):
//  - Inputs f32; output bf16 pairs per complex element, LOW half = IM,
//    HIGH half = RE, at u32 index gidx over [B,T,D,H,W].
//  - Fragment layouts (HW-verified): A: m=lane&15, k=(lane>>4)*8+j ;
//    B: n=lane&15, k=(lane>>4)*8+j ; C/D: col=lane&15, row=(lane>>4)*4+reg.
// R10 (PASSED 1297us): k5 coalesced residual tail + fast gelu.
// R11 (PASSED 1025us): k5 2 m-tiles/wave + pipelined frags + folded gate.
// R12 (PASSED 465us): k3/k4 -> MFMA split-bf16, shuffle-LN.
// R13-R15 (k5 regressions, analyzed): reg budget (c2=64 AGPR + ax) pins k5
//    at 2 waves/SIMD; forced caps spill; prefetch ILP required. R12 best.
// R16 (PASSED 458us): k5 = R12 + aligned Hs pitch 280 + exp2-gelu -> 159us
//    (matched prediction). k5 parked at its verified-best; remaining ~299us
//    is k0,k1,k2,k_scan,k4 (all <159, un-profiled).
// R17 (this round): k2 rewrite with two verified patterns: (a) 2 m-tiles/
//    wave (R11 lever): block = 2 image rows (128px), 4-row halo, each conv
//    weight frag feeds 2 MFMA chains; (b) k3 FUSED into k2 epilogue: conv
//    acc -> bf16 -> Cs[128][136] LDS transpose (k5's verified Hs pattern)
//    -> split-bf16 Menc GEMM (k3 math verbatim) -> outf. Kills 64MB global
//    round trip + one launch. Grid 1024; LDS 69.7KB; k3 kernel deleted.
// ws: 32 MiB bf16 ping + split-bf16 Menc/Mdec frags + swizzled bf16 weights.

typedef unsigned short u16;
typedef unsigned int u32;
typedef __attribute__((ext_vector_type(8))) short bf16x8;
typedef __attribute__((ext_vector_type(4))) float f32x4;

union U16x8 { uint4 u4; uint2 u2[2]; u16 h[8]; bf16x8 v; };

__device__ __forceinline__ float us2f(u16 u) {
  union { u32 i; float f; } c; c.i = ((u32)u) << 16; return c.f;
}
__device__ __forceinline__ u16 f2us(float f) {
  u32 x = __float_as_uint(f);
  u32 r = x + 0x7fffu + ((x >> 16) & 1u);  // RNE
  return (u16)(r >> 16);
}

// ---------------------------------------------------------------------------
// Prep: split-bf16 Menc/Mdec frags + bf16 fragment-swizzled weights:
//  mencs/mdecs [nt8][kk8][lane64][8]  (kk = split*4+ks; k=ks*32+(l>>4)*8+j,
//                                      n=nt*16+(l&15); hi=bf16(M), lo=bf16(M-hi))
//  wcs [tap9][nt8][ks4][lane64][8]  (conv: ic=ks*32+(l>>4)*8+j, oc=nt*16+(l&15))
//  w1s [e4][nt16][ks4][lane64][8]   (k -> 256-col n)
//  w2s [e4][nt8][ks8][lane64][8]    (256-k -> 128-col n)
// ---------------------------------------------------------------------------
__global__ __launch_bounds__(256) void k0_prep(
    const float* __restrict__ conv_w,
    const float* __restrict__ enc_re, const float* __restrict__ enc_im,
    const float* __restrict__ dec_re, const float* __restrict__ dec_im,
    const float* __restrict__ w1, const float* __restrict__ w2,
    u16* __restrict__ mencs, u16* __restrict__ mdecs,
    u16* __restrict__ wcs, u16* __restrict__ w1s, u16* __restrict__ w2s) {
  int idx = blockIdx.x * 256 + threadIdx.x;
  if (idx < 65536) {
    int m = idx >> 15;            // 0=enc, 1=dec
    int z = idx & 32767;
    int s = z >> 14;              // 0=hi, 1=lo
    int q = z & 16383;
    int j = q & 7, lane = (q >> 3) & 63, ks = (q >> 9) & 3, nt = (q >> 11) & 7;
    int k = ks * 32 + (lane >> 4) * 8 + j;
    int n = nt * 16 + (lane & 15);
    const float* mre = m ? dec_re : enc_re;
    const float* mim = m ? dec_im : enc_im;
    float v;
    if (k < 64) v = (n < 64) ?  mre[k * 64 + n]        : mim[k * 64 + n - 64];
    else        v = (n < 64) ? -mim[(k - 64) * 64 + n] : mre[(k - 64) * 64 + n - 64];
    u16 hi = f2us(v);
    u16 val = s ? f2us(v - us2f(hi)) : hi;
    u16* dst = m ? mdecs : mencs;
    dst[((nt * 8 + s * 4 + ks) * 64 + lane) * 8 + j] = val;
  } else if (idx < 212992) {
    int z = idx - 65536;
    int j = z & 7, lane = (z >> 3) & 63, ks = (z >> 9) & 3, nt = (z >> 11) & 7, tap = z >> 14;
    int ic = ks * 32 + (lane >> 4) * 8 + j;
    int oc = nt * 16 + (lane & 15);
    wcs[z] = f2us(conv_w[(oc * 128 + ic) * 9 + tap]);
  } else if (idx < 344064) {
    int z = idx - 212992;
    int j = z & 7, lane = (z >> 3) & 63, ks = (z >> 9) & 3, nt = (z >> 11) & 15, e = z >> 15;
    int k = ks * 32 + (lane >> 4) * 8 + j;
    int nn = nt * 16 + (lane & 15);
    w1s[z] = f2us(w1[e * 32768 + k * 256 + nn]);
  } else if (idx < 475136) {
    int z = idx - 344064;
    int j = z & 7, lane = (z >> 3) & 63, ks = (z >> 9) & 7, nt = (z >> 12) & 7, e = z >> 15;
    int k = ks * 32 + (lane >> 4) * 8 + j;
    int nn = nt * 16 + (lane & 15);
    w2s[z] = f2us(w2[e * 32768 + k * 128 + nn]);
  }
}

// ---------------------------------------------------------------------------
// K1: spatial LayerNorm over channels, f32 NCHW(re|im planes) -> bf16
// channels-last. (unchanged from verified R9)
// ---------------------------------------------------------------------------
__global__ __launch_bounds__(256) void k1_spatial_ln(
    const float* __restrict__ x_re, const float* __restrict__ x_im,
    const float* __restrict__ g, const float* __restrict__ b,
    u16* __restrict__ xn) {
  __shared__ float tile[64 * 129];
  __shared__ float meanA[64], rstdA[64];
  int n = blockIdx.x >> 6, h = blockIdx.x & 63;
  int tid = threadIdx.x;
  for (int k = 0; k < 32; ++k) {
    int flat = tid + k * 256;
    int c = flat >> 6, w = flat & 63;
    float v = (c < 64) ? x_re[n * 262144 + c * 4096 + h * 64 + w]
                       : x_im[n * 262144 + (c - 64) * 4096 + h * 64 + w];
    tile[w * 129 + c] = v;
  }
  __syncthreads();
  int p = tid >> 2, q = tid & 3;
  float s = 0.f, ss = 0.f;
  for (int c = q * 32; c < q * 32 + 32; ++c) {
    float v = tile[p * 129 + c];
    s += v; ss += v * v;
  }
  s += __shfl_xor(s, 1); ss += __shfl_xor(ss, 1);
  s += __shfl_xor(s, 2); ss += __shfl_xor(ss, 2);
  if (q == 0) {
    float m = s * (1.0f / 128.0f);
    float var = ss * (1.0f / 128.0f) - m * m;
    meanA[p] = m; rstdA[p] = rsqrtf(var + 1e-5f);
  }
  __syncthreads();
  int rowbase = (n * 4096 + h * 64) * 128;
  for (int k = 0; k < 32; ++k) {
    int flat = tid + k * 256;
    int pp = flat >> 7, c = flat & 127;
    float v = (tile[pp * 129 + c] - meanA[pp]) * rstdA[pp] * g[c] + b[c];
    xn[rowbase + flat] = f2us(v);
  }
}

// ---------------------------------------------------------------------------
// K2 (MFMA, R17): 3x3 SAME conv + FUSED Menc GEMM. Block = 2 image rows
// (128 px) of one n; 4 waves; wave owns px [wave*16, wave*16+16) in BOTH
// rows (2 m-tiles sharing every conv weight frag -> halved frag traffic,
// 2x MFMA ILP). Xs: 4-row halo (h0-1..h1+1), pitch 132. After conv, acc
// staged as bf16 to Cs[128][136] (aliases Xs; 16B-aligned rows, 4-bank
// row stride) for the channel transpose, then split-bf16 Menc GEMM (k3
// math verbatim: 8 kk ascending) writes outf. Bit-identical to old k2+k3
// (both consumed f2us(conv)).
// ---------------------------------------------------------------------------
__global__ __launch_bounds__(256) void k2_mfma(
    const u16* __restrict__ xn, const u16* __restrict__ wcs,
    const float* __restrict__ conv_b, const u16* __restrict__ ms,
    u16* __restrict__ xs) {
  __shared__ __align__(16) u16 Xs[4 * 66 * 132];   // 69696 B; Cs[128][136] aliases
  int tid = threadIdx.x;
  int wave = tid >> 6, lane = tid & 63;
  int quad = lane >> 4, am = lane & 15;
  int n = blockIdx.x >> 5, hp = blockIdx.x & 31;
  int h0 = hp * 2;

  for (int dh = 0; dh < 4; ++dh) {
    int hs = h0 + dh - 1;
    bool valid = (hs >= 0) && (hs < 64);
    const u16* src = xn + (n * 4096 + hs * 64) * 128;
    for (int c = 0; c < 4; ++c) {
      int f8 = tid + c * 256;            // 1024 chunks of 8 bf16 per row
      int px = f8 >> 4, ch = (f8 & 15) * 8;
      uint2 lo = make_uint2(0, 0), hi = make_uint2(0, 0);
      if (valid) {
        const uint2* s2 = (const uint2*)(src + px * 128 + ch);
        lo = s2[0]; hi = s2[1];
      }
      u16* dst = Xs + (dh * 66 + px + 1) * 132 + ch;
      *(uint2*)dst = lo;
      *(uint2*)(dst + 4) = hi;
    }
  }
  for (int z = tid; z < 1056; z += 256) {  // zero px=-1 / px=64 halos, 4 rows
    int dh = z / 264, r = z % 264;
    int px = (r < 132) ? 0 : 65;
    Xs[(dh * 66 + px) * 132 + (r % 132)] = 0;
  }
  __syncthreads();

  f32x4 acc[2][8];
#pragma unroll
  for (int nt = 0; nt < 8; ++nt) {
    float bv = conv_b[nt * 16 + am];
    acc[0][nt] = (f32x4){bv, bv, bv, bv};
    acc[1][nt] = (f32x4){bv, bv, bv, bv};
  }
  for (int tap = 0; tap < 9; ++tap) {
    int dh = tap / 3, dw = tap % 3;      // output row h0+mt reads Xs row dh+mt
    bf16x8 a[2][4];
#pragma unroll
    for (int mt = 0; mt < 2; ++mt) {
      const u16* arow = Xs + ((dh + mt) * 66 + wave * 16 + am + dw) * 132 + quad * 8;
#pragma unroll
      for (int ks = 0; ks < 4; ++ks) {
        U16x8 t;
        t.u2[0] = *(const uint2*)(arow + ks * 32);
        t.u2[1] = *(const uint2*)(arow + ks * 32 + 4);
        a[mt][ks] = t.v;
      }
    }
    const uint4* wp = (const uint4*)wcs + tap * 2048 + lane;
    uint4 wb[4];
#pragma unroll
    for (int ks = 0; ks < 4; ++ks) wb[ks] = wp[ks * 64];
    for (int nt = 0; nt < 8; ++nt) {
      uint4 wn[4];
      if (nt < 7) {
#pragma unroll
        for (int ks = 0; ks < 4; ++ks) wn[ks] = wp[((nt + 1) * 4 + ks) * 64];
      }
#pragma unroll
      for (int ks = 0; ks < 4; ++ks) {
        U16x8 bf; bf.u4 = wb[ks];
        acc[0][nt] = __builtin_amdgcn_mfma_f32_16x16x32_bf16(a[0][ks], bf.v, acc[0][nt], 0, 0, 0);
        acc[1][nt] = __builtin_amdgcn_mfma_f32_16x16x32_bf16(a[1][ks], bf.v, acc[1][nt], 0, 0, 0);
      }
      if (nt < 7) {
#pragma unroll
        for (int ks = 0; ks < 4; ++ks) wb[ks] = wn[ks];
      }
    }
  }

  // ---- stage conv result to Cs (channel transpose), k5's verified pattern
  __syncthreads();               // all conv A-reads from Xs complete
  u16* Cs = Xs;                  // [128 px][pitch 136] bf16
#pragma unroll
  for (int mt = 0; mt < 2; ++mt)
#pragma unroll
    for (int nt = 0; nt < 8; ++nt)
#pragma unroll
      for (int r = 0; r < 4; ++r)
        Cs[(mt * 64 + wave * 16 + quad * 4 + r) * 136 + nt * 16 + am] =
            f2us(acc[mt][nt][r]);
  __syncthreads();

  // ---- fused Menc GEMM (k3 verbatim math: split-bf16, kk 0..7 ascending)
  bf16x8 a2[2][4];
#pragma unroll
  for (int mt = 0; mt < 2; ++mt) {
    const u16* crow = Cs + (mt * 64 + wave * 16 + am) * 136;
#pragma unroll
    for (int ks = 0; ks < 4; ++ks) {
      U16x8 t; t.u4 = *(const uint4*)(crow + ks * 32 + quad * 8);
      a2[mt][ks] = t.v;
    }
  }
  const uint4* mp = (const uint4*)ms + lane;
  uint4 wb[8];
#pragma unroll
  for (int kk = 0; kk < 8; ++kk) wb[kk] = mp[kk * 64];
  int rowg0 = n * 4096 + h0 * 64 + wave * 16;
  for (int nt = 0; nt < 8; ++nt) {
    uint4 wn[8];
    if (nt < 7) {
#pragma unroll
      for (int kk = 0; kk < 8; ++kk) wn[kk] = mp[((nt + 1) * 8 + kk) * 64];
    }
    f32x4 ca = (f32x4){0.f, 0.f, 0.f, 0.f};
    f32x4 cb = (f32x4){0.f, 0.f, 0.f, 0.f};
#pragma unroll
    for (int kk = 0; kk < 8; ++kk) {
      U16x8 bf; bf.u4 = wb[kk];
      ca = __builtin_amdgcn_mfma_f32_16x16x32_bf16(a2[0][kk & 3], bf.v, ca, 0, 0, 0);
      cb = __builtin_amdgcn_mfma_f32_16x16x32_bf16(a2[1][kk & 3], bf.v, cb, 0, 0, 0);
    }
#pragma unroll
    for (int r = 0; r < 4; ++r) {
      xs[(rowg0 + quad * 4 + r) * 128 + nt * 16 + am]      = f2us(ca[r]);
      xs[(rowg0 + 64 + quad * 4 + r) * 128 + nt * 16 + am] = f2us(cb[r]);
    }
    if (nt < 7) {
#pragma unroll
      for (int kk = 0; kk < 8; ++kk) wb[kk] = wn[kk];
    }
  }
}

// ---------------------------------------------------------------------------
// K_scan: temporal ZOH scan T=16, in place (unchanged from verified R9).
// ---------------------------------------------------------------------------
__global__ __launch_bounds__(256) void k_scan(
    u16* __restrict__ u, const float* __restrict__ dt,
    const float* __restrict__ alpha, const float* __restrict__ omega,
    const float* __restrict__ ns_p) {
  int flat = blockIdx.x * 256 + threadIdx.x;
  int d = flat & 63;
  int hw = (flat >> 6) & 4095;
  int b = flat >> 18;
  float a = alpha[d];
  float sp = (a > 20.f) ? a : log1pf(expf(a));
  float lr = -sp, li = omega[d];
  float inv_l2 = 1.0f / (lr * lr + li * li);
  float ns = ns_p[0];
  float yr = 0.f, yi = 0.f;
  const int stride = 4096 * 128;
  int base0 = b * 16 * stride + hw * 128 + d;
  for (int t = 0; t < 16; ++t) {
    float dtv = dt[t];
    float er = expf(lr * dtv);
    float ang = li * dtv;
    float dr = er * cosf(ang), di = er * sinf(ang);
    float fr = ((dr - 1.f) * lr + di * li) * inv_l2;
    float fi = (di * lr - (dr - 1.f) * li) * inv_l2;
    int idx = base0 + t * stride;
    float ur = us2f(u[idx]), ui = us2f(u[idx + 64]);
    float usr = ur * fr - ui * fi;
    float usi = ur * fi + ui * fr;
    float nyr = dr * yr - di * yi + usr;
    float nyi = dr * yi + di * yr + usi;
    yr = nyr; yi = nyi;
    float sc = 1.0f + ns * sqrtf(dtv);
    u[idx] = f2us(yr * sc);
    u[idx + 64] = f2us(yi * sc);
  }
}

// ---------------------------------------------------------------------------
// K4 (MFMA, R12): xo <- LN(U @ Mdec), split-bf16 weights, k3 template +
// wave-shuffle LayerNorm. C/D layout spreads a pixel's 128 channels over
// am-lanes(16) x nt(8): per-(mt,r) partial over nt, then shfl_xor 1/2/4/8
// reduces over am-lanes. No LDS.
// ---------------------------------------------------------------------------
__global__ __launch_bounds__(256) void k4_mfma(
    const u16* __restrict__ U, const u16* __restrict__ ms,
    const float* __restrict__ g, const float* __restrict__ bb,
    u16* __restrict__ xo) {
  int tid = threadIdx.x;
  int wave = tid >> 6, lane = tid & 63;
  int quad = lane >> 4, am = lane & 15;
  int rowbase = blockIdx.x * 128 + wave * 32;

  bf16x8 ax[2][4];
#pragma unroll
  for (int mt = 0; mt < 2; ++mt) {
    const uint4* ar = (const uint4*)(U + (rowbase + mt * 16 + am) * 128 + quad * 8);
#pragma unroll
    for (int ks = 0; ks < 4; ++ks) { U16x8 t; t.u4 = ar[ks * 4]; ax[mt][ks] = t.v; }
  }
  float gv[8], bv[8];
#pragma unroll
  for (int nt = 0; nt < 8; ++nt) { gv[nt] = g[nt * 16 + am]; bv[nt] = bb[nt * 16 + am]; }

  const uint4* mp = (const uint4*)ms + lane;
  f32x4 acc[2][8];
#pragma unroll
  for (int mt = 0; mt < 2; ++mt)
#pragma unroll
    for (int nt = 0; nt < 8; ++nt) acc[mt][nt] = (f32x4){0.f, 0.f, 0.f, 0.f};

  uint4 wb[8];
#pragma unroll
  for (int kk = 0; kk < 8; ++kk) wb[kk] = mp[kk * 64];
  for (int nt = 0; nt < 8; ++nt) {
    uint4 wn[8];
    if (nt < 7) {
#pragma unroll
      for (int kk = 0; kk < 8; ++kk) wn[kk] = mp[((nt + 1) * 8 + kk) * 64];
    }
#pragma unroll
    for (int kk = 0; kk < 8; ++kk) {
      U16x8 bf; bf.u4 = wb[kk];
      acc[0][nt] = __builtin_amdgcn_mfma_f32_16x16x32_bf16(ax[0][kk & 3], bf.v, acc[0][nt], 0, 0, 0);
      acc[1][nt] = __builtin_amdgcn_mfma_f32_16x16x32_bf16(ax[1][kk & 3], bf.v, acc[1][nt], 0, 0, 0);
    }
    if (nt < 7) {
#pragma unroll
      for (int kk = 0; kk < 8; ++kk) wb[kk] = wn[kk];
    }
  }

  // wave-shuffle LayerNorm + store
#pragma unroll
  for (int mt = 0; mt < 2; ++mt) {
#pragma unroll
    for (int r = 0; r < 4; ++r) {
      float s = 0.f, ss = 0.f;
#pragma unroll
      for (int nt = 0; nt < 8; ++nt) { float v = acc[mt][nt][r]; s += v; ss += v * v; }
      s += __shfl_xor(s, 1); ss += __shfl_xor(ss, 1);
      s += __shfl_xor(s, 2); ss += __shfl_xor(ss, 2);
      s += __shfl_xor(s, 4); ss += __shfl_xor(ss, 4);
      s += __shfl_xor(s, 8); ss += __shfl_xor(ss, 8);
      float m = s * (1.0f / 128.0f);
      float var = ss * (1.0f / 128.0f) - m * m;
      float rstd = rsqrtf(var + 1e-5f);
      u16* xop = xo + (rowbase + mt * 16 + quad * 4 + r) * 128 + am;
#pragma unroll
      for (int nt = 0; nt < 8; ++nt)
        xop[nt * 16] = f2us((acc[mt][nt][r] - m) * rstd * gv[nt] + bv[nt]);
    }
  }
}

// ---------------------------------------------------------------------------
// K5 (MFMA): soft MoE + residual. R16 verified-best: R12 structure (2
// m-tiles/wave, full-H LDS, 1-deep weight pipelines, folded gate, Os
// transpose tail) + Hs pitch 280 (aligned b128 a2 reads) + exp2-gelu.
// Out: LOW=im, HIGH=re u32 pack at gidx (verified T2 layout).
// ---------------------------------------------------------------------------
__global__ __launch_bounds__(256) void k5_mfma(
    const u16* __restrict__ xo, const u16* __restrict__ w1s,
    const u16* __restrict__ w2s, const float* __restrict__ w_router,
    const float* __restrict__ x_re, const float* __restrict__ x_im,
    u16* __restrict__ out) {
  __shared__ __align__(16) u16 Hs[128 * 280];   // 71680 B; Os f32[128][129] aliases
  __shared__ float gate_s[128 * 4];
  int tid = threadIdx.x;
  int wave = tid >> 6, lane = tid & 63;
  int quad = lane >> 4, am = lane & 15;
  int rowbase = blockIdx.x * 128 + wave * 32;

  // router gates: lane -> (px = pp*16+am, e=quad); shuffle softmax over quads
  for (int pp = 0; pp < 2; ++pp) {
    int pxl = wave * 32 + pp * 16 + am;
    const uint4* xr = (const uint4*)(xo + (blockIdx.x * 128 + pxl) * 128);
    float acc = 0.f;
    for (int c8 = 0; c8 < 16; ++c8) {
      U16x8 t; t.u4 = xr[c8];
#pragma unroll
      for (int j = 0; j < 8; ++j)
        acc += us2f(t.h[j]) * w_router[(c8 * 8 + j) * 4 + quad];
    }
    float mx = fmaxf(acc, __shfl_xor(acc, 16));
    mx = fmaxf(mx, __shfl_xor(mx, 32));
    float ex = __expf(acc - mx);
    float sm = ex + __shfl_xor(ex, 16);
    sm += __shfl_xor(sm, 32);
    gate_s[pxl * 4 + quad] = ex / sm;
  }

  // A-frags of X, 2 m-tiles (constant across experts)
  bf16x8 ax[2][4];
#pragma unroll
  for (int mt = 0; mt < 2; ++mt) {
    const uint4* ar = (const uint4*)(xo + (rowbase + mt * 16 + am) * 128 + quad * 8);
#pragma unroll
    for (int ks = 0; ks < 4; ++ks) { U16x8 t; t.u4 = ar[ks * 4]; ax[mt][ks] = t.v; }
  }

  // c2[mt][nt] accumulates gated expert outputs across ALL experts
  f32x4 c2[2][8];
#pragma unroll
  for (int mt = 0; mt < 2; ++mt)
#pragma unroll
    for (int nt = 0; nt < 8; ++nt) c2[mt][nt] = (f32x4){0.f, 0.f, 0.f, 0.f};

  // gelu(v)*g = gv - gv*rcp(1 + exp2(v*(GA2+GB2*v^2))), log2e pre-folded:
  // GA2 = 2*0.7978845608*log2e, GB2 = GA2*0.044715
  const float GA2 = 2.3022085f, GB2 = 0.10294348f;

  for (int e = 0; e < 4; ++e) {
    // ---- stage a: H = gelu(X @ W1[e]) * gate  [32 px x 256 hid per wave]
    const uint4* w1p = (const uint4*)w1s + e * 4096 + lane;
    uint4 wb[4];
#pragma unroll
    for (int ks = 0; ks < 4; ++ks) wb[ks] = w1p[ks * 64];
    for (int nt = 0; nt < 16; ++nt) {
      uint4 wn[4];
      if (nt < 15) {
#pragma unroll
        for (int ks = 0; ks < 4; ++ks) wn[ks] = w1p[((nt + 1) * 4 + ks) * 64];
      }
      f32x4 c1a = (f32x4){0.f, 0.f, 0.f, 0.f};
      f32x4 c1b = (f32x4){0.f, 0.f, 0.f, 0.f};
#pragma unroll
      for (int ks = 0; ks < 4; ++ks) {
        U16x8 bf; bf.u4 = wb[ks];
        c1a = __builtin_amdgcn_mfma_f32_16x16x32_bf16(ax[0][ks], bf.v, c1a, 0, 0, 0);
        c1b = __builtin_amdgcn_mfma_f32_16x16x32_bf16(ax[1][ks], bf.v, c1b, 0, 0, 0);
      }
#pragma unroll
      for (int r = 0; r < 4; ++r) {
        float v = c1a[r];
        float gv0 = gate_s[(wave * 32 + quad * 4 + r) * 4 + e] * v;
        float rc = __builtin_amdgcn_rcpf(
            1.0f + __builtin_amdgcn_exp2f(v * (GA2 + GB2 * v * v)));
        Hs[(wave * 32 + quad * 4 + r) * 280 + nt * 16 + am] = f2us(gv0 - gv0 * rc);
        v = c1b[r];
        float gv1 = gate_s[(wave * 32 + 16 + quad * 4 + r) * 4 + e] * v;
        rc = __builtin_amdgcn_rcpf(
            1.0f + __builtin_amdgcn_exp2f(v * (GA2 + GB2 * v * v)));
        Hs[(wave * 32 + 16 + quad * 4 + r) * 280 + nt * 16 + am] = f2us(gv1 - gv1 * rc);
      }
      if (nt < 15) {
#pragma unroll
        for (int ks = 0; ks < 4; ++ks) wb[ks] = wn[ks];
      }
    }
    // ---- stage b: c2 += (g*H) @ W2[e]  [32 px x 128 out per wave]
    const uint4* w2p = (const uint4*)w2s + e * 4096 + lane;
    uint4 wb2[8];
#pragma unroll
    for (int nt = 0; nt < 8; ++nt) wb2[nt] = w2p[(nt * 8) * 64];
    for (int ks = 0; ks < 8; ++ks) {
      uint4 wn2[8];
      if (ks < 7) {
#pragma unroll
        for (int nt = 0; nt < 8; ++nt) wn2[nt] = w2p[(nt * 8 + ks + 1) * 64];
      }
      U16x8 a2[2];
#pragma unroll
      for (int mt = 0; mt < 2; ++mt)
        a2[mt].u4 = *(const uint4*)(Hs + (wave * 32 + mt * 16 + am) * 280 + ks * 32 + quad * 8);
#pragma unroll
      for (int nt = 0; nt < 8; ++nt) {
        U16x8 bf; bf.u4 = wb2[nt];
        c2[0][nt] = __builtin_amdgcn_mfma_f32_16x16x32_bf16(a2[0].v, bf.v, c2[0][nt], 0, 0, 0);
        c2[1][nt] = __builtin_amdgcn_mfma_f32_16x16x32_bf16(a2[1].v, bf.v, c2[1][nt], 0, 0, 0);
      }
      if (ks < 7) {
#pragma unroll
        for (int nt = 0; nt < 8; ++nt) wb2[nt] = wn2[nt];
      }
    }
  }

  // ---- coalesced residual + store via LDS transpose (verified R10/R12) ----
  // Os[d][px]: d in [0,128) (0..63 = re, 64..127 = im), px in [0,128).
  __syncthreads();               // all waves done reading Hs
  float* Os = (float*)Hs;
#pragma unroll
  for (int nt = 0; nt < 4; ++nt)
#pragma unroll
    for (int mt = 0; mt < 2; ++mt)
#pragma unroll
      for (int r = 0; r < 4; ++r) {
        int pxl = wave * 32 + mt * 16 + quad * 4 + r;
        Os[(nt * 16 + am) * 129 + pxl]      = c2[mt][nt][r];      // re
        Os[(64 + nt * 16 + am) * 129 + pxl] = c2[mt][nt + 4][r];  // im
      }
  __syncthreads();
  int nb  = (blockIdx.x * 128) >> 12;      // batch-time index
  int hw0 = (blockIdx.x * 128) & 4095;     // contiguous hw range of this block
#pragma unroll
  for (int k = 0; k < 32; ++k) {
    int flat = tid + k * 256;              // 8192 (d,px) pairs
    int d = flat >> 7, px = flat & 127;
    int gidx = (nb * 64 + d) * 4096 + hw0 + px;
    float rr = x_re[gidx] + Os[d * 129 + px];
    float ii = x_im[gidx] + Os[(64 + d) * 129 + px];
    ((u32*)out)[gidx] = (u32)f2us(ii) | ((u32)f2us(rr) << 16);
  }
}

// ---------------------------------------------------------------------------
extern "C" void kernel_launch(void* const* d_in, const int* in_sizes, int n_in,
                              void* d_out, int out_size, void* d_ws, size_t ws_size,
                              hipStream_t stream) {
  const float* x_re     = (const float*)d_in[0];
  const float* x_im     = (const float*)d_in[1];
  const float* dt       = (const float*)d_in[2];
  const float* ln_s_g   = (const float*)d_in[3];
  const float* ln_s_b   = (const float*)d_in[4];
  const float* conv_w   = (const float*)d_in[5];
  const float* conv_b   = (const float*)d_in[6];
  const float* ln_t_g   = (const float*)d_in[7];
  const float* ln_t_b   = (const float*)d_in[8];
  const float* enc_re   = (const float*)d_in[9];
  const float* enc_im   = (const float*)d_in[10];
  const float* dec_re   = (const float*)d_in[11];
  const float* dec_im   = (const float*)d_in[12];
  const float* alpha    = (const float*)d_in[13];
  const float* omega    = (const float*)d_in[14];
  // 15..20: wg, bg, p_re, p_im, w_drift, b_drift -> dead code in reference
  const float* w_router = (const float*)d_in[21];
  const float* w1       = (const float*)d_in[22];
  const float* w2       = (const float*)d_in[23];
  const float* ns       = (const float*)d_in[24];

  u16*   buf   = (u16*)d_ws;                             // 32 MiB bf16 ping
  u16*   mencs = (u16*)((char*)d_ws + 33554432);         // 32,768 bf16 (hi+lo)
  u16*   mdecs = mencs + 32768;                          // 32,768 bf16 (hi+lo)
  u16*   wcs   = mdecs + 32768;                          // 147,456 bf16
  u16*   w1s   = wcs + 147456;                           // 131,072 bf16
  u16*   w2s   = w1s + 131072;                           // 131,072 bf16
  u16*   outf  = (u16*)d_out;                            // 32 MiB bf16 pong

  k0_prep<<<1856, 256, 0, stream>>>(conv_w, enc_re, enc_im, dec_re, dec_im,
                                    w1, w2, mencs, mdecs, wcs, w1s, w2s);
  k1_spatial_ln<<<2048, 256, 0, stream>>>(x_re, x_im, ln_s_g, ln_s_b, buf);
  k2_mfma<<<1024, 256, 0, stream>>>(buf, wcs, conv_b, mencs, outf);
  k_scan<<<2048, 256, 0, stream>>>(outf, dt, alpha, omega, ns);
  k4_mfma<<<1024, 256, 0, stream>>>(outf, mdecs, ln_t_g, ln_t_b, buf);
  k5_mfma<<<1024, 256, 0, stream>>>(buf, w1s, w2s, w_router, x_re, x_im, outf);
}

// Round 9
// 456.802 us; speedup vs baseline: 1.0184x; 1.0184x over previous
//
#include <hip/hip_runtime.h>
#include <hip/hip_bf16.h>

// Problem dims
#define BB 2
#define TT 16
#define DD 64
#define HH 64
#define WW 64
#define NPIX 131072

// ESTABLISHED (R0-R9, R9 PASSED @ 6288us; prev session best 1320us):
//  - Inputs f32; output bf16 pairs per complex element, LOW half = IM,
//    HIGH half = RE, at u32 index gidx over [B,T,D,H,W].
//  - Fragment layouts (HW-verified): A: m=lane&15, k=(lane>>4)*8+j ;
//    B: n=lane&15, k=(lane>>4)*8+j ; C/D: col=lane&15, row=(lane>>4)*4+reg.
// R10 (PASSED 1297us): k5 coalesced residual tail + fast gelu.
// R11 (PASSED 1025us): k5 2 m-tiles/wave + pipelined frags + folded gate.
// R12 (PASSED 465us): k3/k4 -> MFMA split-bf16, shuffle-LN.
// R13-R15 (k5 regressions, analyzed): reg budget pins k5 at 2 waves/SIMD;
//    forced caps spill; prefetch ILP required. R12 structure best.
// R16 (PASSED 458us): k5 = R12 + aligned Hs pitch 280 + exp2-gelu -> 159us.
//    k5 parked at verified-best.
// R17 (NEUTRAL 465us): 2-row fused k2+k3. Fusion gain cancelled by conv
//    occupancy loss (4-row halo 69.7KB -> 2 blk/CU vs 1-row 52.3KB -> 3).
//    Lesson re-confirmed: TLP > tile-ILP at these latencies.
// R18 (this round): keep fusion, revert conv to 1-ROW blocks (R12 verbatim
//    conv: 3-row halo, 52.3KB, 3 blk/CU, grid 2048). Epilogue: acc ->
//    f2us -> Cs[64][136] (aliases Xs, no LDS growth) -> split-bf16 Menc
//    GEMM (k3 math verbatim, kk 0..7 ascending -> bit-identical), nt-pair
//    2-chain ILP, A-frags from LDS. k3's launch + 64MB round trip gone.
// ws: 32 MiB bf16 ping + split-bf16 Menc/Mdec frags + swizzled bf16 weights.

typedef unsigned short u16;
typedef unsigned int u32;
typedef __attribute__((ext_vector_type(8))) short bf16x8;
typedef __attribute__((ext_vector_type(4))) float f32x4;

union U16x8 { uint4 u4; uint2 u2[2]; u16 h[8]; bf16x8 v; };

__device__ __forceinline__ float us2f(u16 u) {
  union { u32 i; float f; } c; c.i = ((u32)u) << 16; return c.f;
}
__device__ __forceinline__ u16 f2us(float f) {
  u32 x = __float_as_uint(f);
  u32 r = x + 0x7fffu + ((x >> 16) & 1u);  // RNE
  return (u16)(r >> 16);
}

// ---------------------------------------------------------------------------
// Prep: split-bf16 Menc/Mdec frags + bf16 fragment-swizzled weights:
//  mencs/mdecs [nt8][kk8][lane64][8]  (kk = split*4+ks; k=ks*32+(l>>4)*8+j,
//                                      n=nt*16+(l&15); hi=bf16(M), lo=bf16(M-hi))
//  wcs [tap9][nt8][ks4][lane64][8]  (conv: ic=ks*32+(l>>4)*8+j, oc=nt*16+(l&15))
//  w1s [e4][nt16][ks4][lane64][8]   (k -> 256-col n)
//  w2s [e4][nt8][ks8][lane64][8]    (256-k -> 128-col n)
// ---------------------------------------------------------------------------
__global__ __launch_bounds__(256) void k0_prep(
    const float* __restrict__ conv_w,
    const float* __restrict__ enc_re, const float* __restrict__ enc_im,
    const float* __restrict__ dec_re, const float* __restrict__ dec_im,
    const float* __restrict__ w1, const float* __restrict__ w2,
    u16* __restrict__ mencs, u16* __restrict__ mdecs,
    u16* __restrict__ wcs, u16* __restrict__ w1s, u16* __restrict__ w2s) {
  int idx = blockIdx.x * 256 + threadIdx.x;
  if (idx < 65536) {
    int m = idx >> 15;            // 0=enc, 1=dec
    int z = idx & 32767;
    int s = z >> 14;              // 0=hi, 1=lo
    int q = z & 16383;
    int j = q & 7, lane = (q >> 3) & 63, ks = (q >> 9) & 3, nt = (q >> 11) & 7;
    int k = ks * 32 + (lane >> 4) * 8 + j;
    int n = nt * 16 + (lane & 15);
    const float* mre = m ? dec_re : enc_re;
    const float* mim = m ? dec_im : enc_im;
    float v;
    if (k < 64) v = (n < 64) ?  mre[k * 64 + n]        : mim[k * 64 + n - 64];
    else        v = (n < 64) ? -mim[(k - 64) * 64 + n] : mre[(k - 64) * 64 + n - 64];
    u16 hi = f2us(v);
    u16 val = s ? f2us(v - us2f(hi)) : hi;
    u16* dst = m ? mdecs : mencs;
    dst[((nt * 8 + s * 4 + ks) * 64 + lane) * 8 + j] = val;
  } else if (idx < 212992) {
    int z = idx - 65536;
    int j = z & 7, lane = (z >> 3) & 63, ks = (z >> 9) & 3, nt = (z >> 11) & 7, tap = z >> 14;
    int ic = ks * 32 + (lane >> 4) * 8 + j;
    int oc = nt * 16 + (lane & 15);
    wcs[z] = f2us(conv_w[(oc * 128 + ic) * 9 + tap]);
  } else if (idx < 344064) {
    int z = idx - 212992;
    int j = z & 7, lane = (z >> 3) & 63, ks = (z >> 9) & 3, nt = (z >> 11) & 15, e = z >> 15;
    int k = ks * 32 + (lane >> 4) * 8 + j;
    int nn = nt * 16 + (lane & 15);
    w1s[z] = f2us(w1[e * 32768 + k * 256 + nn]);
  } else if (idx < 475136) {
    int z = idx - 344064;
    int j = z & 7, lane = (z >> 3) & 63, ks = (z >> 9) & 7, nt = (z >> 12) & 7, e = z >> 15;
    int k = ks * 32 + (lane >> 4) * 8 + j;
    int nn = nt * 16 + (lane & 15);
    w2s[z] = f2us(w2[e * 32768 + k * 128 + nn]);
  }
}

// ---------------------------------------------------------------------------
// K1: spatial LayerNorm over channels, f32 NCHW(re|im planes) -> bf16
// channels-last. (unchanged from verified R9)
// ---------------------------------------------------------------------------
__global__ __launch_bounds__(256) void k1_spatial_ln(
    const float* __restrict__ x_re, const float* __restrict__ x_im,
    const float* __restrict__ g, const float* __restrict__ b,
    u16* __restrict__ xn) {
  __shared__ float tile[64 * 129];
  __shared__ float meanA[64], rstdA[64];
  int n = blockIdx.x >> 6, h = blockIdx.x & 63;
  int tid = threadIdx.x;
  for (int k = 0; k < 32; ++k) {
    int flat = tid + k * 256;
    int c = flat >> 6, w = flat & 63;
    float v = (c < 64) ? x_re[n * 262144 + c * 4096 + h * 64 + w]
                       : x_im[n * 262144 + (c - 64) * 4096 + h * 64 + w];
    tile[w * 129 + c] = v;
  }
  __syncthreads();
  int p = tid >> 2, q = tid & 3;
  float s = 0.f, ss = 0.f;
  for (int c = q * 32; c < q * 32 + 32; ++c) {
    float v = tile[p * 129 + c];
    s += v; ss += v * v;
  }
  s += __shfl_xor(s, 1); ss += __shfl_xor(ss, 1);
  s += __shfl_xor(s, 2); ss += __shfl_xor(ss, 2);
  if (q == 0) {
    float m = s * (1.0f / 128.0f);
    float var = ss * (1.0f / 128.0f) - m * m;
    meanA[p] = m; rstdA[p] = rsqrtf(var + 1e-5f);
  }
  __syncthreads();
  int rowbase = (n * 4096 + h * 64) * 128;
  for (int k = 0; k < 32; ++k) {
    int flat = tid + k * 256;
    int pp = flat >> 7, c = flat & 127;
    float v = (tile[pp * 129 + c] - meanA[pp]) * rstdA[pp] * g[c] + b[c];
    xn[rowbase + flat] = f2us(v);
  }
}

// ---------------------------------------------------------------------------
// K2 (MFMA, R18): 3x3 SAME conv + FUSED Menc GEMM, 1-ROW blocks. Conv part
// = R12 verbatim (one (n,h) row of 64px, 4 waves (wave=mt), 3-row halo,
// pitch 132, 1-deep weight pipeline): 52.3KB LDS -> 3 blocks/CU.
// Epilogue: acc -> f2us -> Cs[64][136] (aliases Xs; 272B rows, 16B-aligned
// -> single b128 a2 reads), barrier, split-bf16 Menc GEMM (k3 math
// verbatim: per output kk 0..7 ascending -> bit-identical), nt-pairs for
// 2-chain ILP, stores xs directly. Replaces the old separate k3.
// ---------------------------------------------------------------------------
__global__ __launch_bounds__(256) void k2_mfma(
    const u16* __restrict__ xn, const u16* __restrict__ wcs,
    const float* __restrict__ conv_b, const u16* __restrict__ ms,
    u16* __restrict__ xs) {
  __shared__ __align__(16) u16 Xs[3 * 66 * 132];   // 52272 B; Cs[64][136] aliases
  int tid = threadIdx.x;
  int wave = tid >> 6, lane = tid & 63;
  int quad = lane >> 4, am = lane & 15;
  int n = blockIdx.x >> 6, h = blockIdx.x & 63;

  for (int dh = 0; dh < 3; ++dh) {
    int hs = h + dh - 1;
    bool valid = (hs >= 0) && (hs < 64);
    const u16* src = xn + (n * 4096 + hs * 64) * 128;
    for (int c = 0; c < 4; ++c) {
      int f8 = tid + c * 256;            // 1024 chunks of 8 bf16
      int px = f8 >> 4, ch = (f8 & 15) * 8;
      uint2 lo = make_uint2(0, 0), hi = make_uint2(0, 0);
      if (valid) {
        const uint2* s2 = (const uint2*)(src + px * 128 + ch);
        lo = s2[0]; hi = s2[1];
      }
      u16* dst = Xs + (dh * 66 + px + 1) * 132 + ch;
      *(uint2*)dst = lo;
      *(uint2*)(dst + 4) = hi;
    }
  }
  for (int z = tid; z < 792; z += 256) {   // zero px=-1 / px=64 halos
    int dh = z / 264, r = z % 264;
    int px = (r < 132) ? 0 : 65;
    Xs[(dh * 66 + px) * 132 + (r % 132)] = 0;
  }
  __syncthreads();

  f32x4 acc[8];
#pragma unroll
  for (int nt = 0; nt < 8; ++nt) {
    float bv = conv_b[nt * 16 + am];
    acc[nt] = (f32x4){bv, bv, bv, bv};
  }
  int mt = wave;
  for (int tap = 0; tap < 9; ++tap) {
    int dh = tap / 3, dw = tap % 3;      // dw: 0,1,2 -> shift -1,0,+1 (halo idx)
    const u16* arow = Xs + (dh * 66 + mt * 16 + am + dw) * 132 + quad * 8;
    bf16x8 a[4];
#pragma unroll
    for (int ks = 0; ks < 4; ++ks) {
      U16x8 t;
      t.u2[0] = *(const uint2*)(arow + ks * 32);
      t.u2[1] = *(const uint2*)(arow + ks * 32 + 4);
      a[ks] = t.v;
    }
    const uint4* wp = (const uint4*)wcs + tap * 2048 + lane;
    uint4 wb[4];
#pragma unroll
    for (int ks = 0; ks < 4; ++ks) wb[ks] = wp[ks * 64];
    for (int nt = 0; nt < 8; ++nt) {
      uint4 wn[4];
      if (nt < 7) {
#pragma unroll
        for (int ks = 0; ks < 4; ++ks) wn[ks] = wp[((nt + 1) * 4 + ks) * 64];
      }
#pragma unroll
      for (int ks = 0; ks < 4; ++ks) {
        U16x8 bf; bf.u4 = wb[ks];
        acc[nt] = __builtin_amdgcn_mfma_f32_16x16x32_bf16(a[ks], bf.v, acc[nt], 0, 0, 0);
      }
      if (nt < 7) {
#pragma unroll
        for (int ks = 0; ks < 4; ++ks) wb[ks] = wn[ks];
      }
    }
  }

  // ---- stage conv result to Cs (channel transpose; f2us matches old k2
  // global store, so downstream math is bit-identical to old k2+k3)
  __syncthreads();               // all conv A-reads from Xs complete
  u16* Cs = Xs;                  // [64 px][pitch 136] bf16 = 17408 B
#pragma unroll
  for (int nt = 0; nt < 8; ++nt)
#pragma unroll
    for (int r = 0; r < 4; ++r)
      Cs[(wave * 16 + quad * 4 + r) * 136 + nt * 16 + am] = f2us(acc[nt][r]);
  __syncthreads();

  // ---- fused Menc GEMM (k3 verbatim math: split-bf16, kk 0..7 ascending)
  bf16x8 a2[4];
  {
    const u16* crow = Cs + (wave * 16 + am) * 136;
#pragma unroll
    for (int ks = 0; ks < 4; ++ks) {
      U16x8 t; t.u4 = *(const uint4*)(crow + ks * 32 + quad * 8);
      a2[ks] = t.v;
    }
  }
  const uint4* mp = (const uint4*)ms + lane;
  int rowg = n * 4096 + h * 64 + wave * 16;
  for (int p = 0; p < 4; ++p) {            // nt-pairs: 2 indep chains of ILP
    f32x4 ca = (f32x4){0.f, 0.f, 0.f, 0.f};
    f32x4 cb = (f32x4){0.f, 0.f, 0.f, 0.f};
#pragma unroll
    for (int kk = 0; kk < 8; ++kk) {
      U16x8 b0; b0.u4 = mp[((2 * p) * 8 + kk) * 64];
      U16x8 b1; b1.u4 = mp[((2 * p + 1) * 8 + kk) * 64];
      ca = __builtin_amdgcn_mfma_f32_16x16x32_bf16(a2[kk & 3], b0.v, ca, 0, 0, 0);
      cb = __builtin_amdgcn_mfma_f32_16x16x32_bf16(a2[kk & 3], b1.v, cb, 0, 0, 0);
    }
#pragma unroll
    for (int r = 0; r < 4; ++r) {
      xs[(rowg + quad * 4 + r) * 128 + (2 * p) * 16 + am]     = f2us(ca[r]);
      xs[(rowg + quad * 4 + r) * 128 + (2 * p + 1) * 16 + am] = f2us(cb[r]);
    }
  }
}

// ---------------------------------------------------------------------------
// K_scan: temporal ZOH scan T=16, in place (unchanged from verified R9).
// ---------------------------------------------------------------------------
__global__ __launch_bounds__(256) void k_scan(
    u16* __restrict__ u, const float* __restrict__ dt,
    const float* __restrict__ alpha, const float* __restrict__ omega,
    const float* __restrict__ ns_p) {
  int flat = blockIdx.x * 256 + threadIdx.x;
  int d = flat & 63;
  int hw = (flat >> 6) & 4095;
  int b = flat >> 18;
  float a = alpha[d];
  float sp = (a > 20.f) ? a : log1pf(expf(a));
  float lr = -sp, li = omega[d];
  float inv_l2 = 1.0f / (lr * lr + li * li);
  float ns = ns_p[0];
  float yr = 0.f, yi = 0.f;
  const int stride = 4096 * 128;
  int base0 = b * 16 * stride + hw * 128 + d;
  for (int t = 0; t < 16; ++t) {
    float dtv = dt[t];
    float er = expf(lr * dtv);
    float ang = li * dtv;
    float dr = er * cosf(ang), di = er * sinf(ang);
    float fr = ((dr - 1.f) * lr + di * li) * inv_l2;
    float fi = (di * lr - (dr - 1.f) * li) * inv_l2;
    int idx = base0 + t * stride;
    float ur = us2f(u[idx]), ui = us2f(u[idx + 64]);
    float usr = ur * fr - ui * fi;
    float usi = ur * fi + ui * fr;
    float nyr = dr * yr - di * yi + usr;
    float nyi = dr * yi + di * yr + usi;
    yr = nyr; yi = nyi;
    float sc = 1.0f + ns * sqrtf(dtv);
    u[idx] = f2us(yr * sc);
    u[idx + 64] = f2us(yi * sc);
  }
}

// ---------------------------------------------------------------------------
// K4 (MFMA, R12): xo <- LN(U @ Mdec), split-bf16 weights, k3 template +
// wave-shuffle LayerNorm. C/D layout spreads a pixel's 128 channels over
// am-lanes(16) x nt(8): per-(mt,r) partial over nt, then shfl_xor 1/2/4/8
// reduces over am-lanes. No LDS.
// ---------------------------------------------------------------------------
__global__ __launch_bounds__(256) void k4_mfma(
    const u16* __restrict__ U, const u16* __restrict__ ms,
    const float* __restrict__ g, const float* __restrict__ bb,
    u16* __restrict__ xo) {
  int tid = threadIdx.x;
  int wave = tid >> 6, lane = tid & 63;
  int quad = lane >> 4, am = lane & 15;
  int rowbase = blockIdx.x * 128 + wave * 32;

  bf16x8 ax[2][4];
#pragma unroll
  for (int mt = 0; mt < 2; ++mt) {
    const uint4* ar = (const uint4*)(U + (rowbase + mt * 16 + am) * 128 + quad * 8);
#pragma unroll
    for (int ks = 0; ks < 4; ++ks) { U16x8 t; t.u4 = ar[ks * 4]; ax[mt][ks] = t.v; }
  }
  float gv[8], bv[8];
#pragma unroll
  for (int nt = 0; nt < 8; ++nt) { gv[nt] = g[nt * 16 + am]; bv[nt] = bb[nt * 16 + am]; }

  const uint4* mp = (const uint4*)ms + lane;
  f32x4 acc[2][8];
#pragma unroll
  for (int mt = 0; mt < 2; ++mt)
#pragma unroll
    for (int nt = 0; nt < 8; ++nt) acc[mt][nt] = (f32x4){0.f, 0.f, 0.f, 0.f};

  uint4 wb[8];
#pragma unroll
  for (int kk = 0; kk < 8; ++kk) wb[kk] = mp[kk * 64];
  for (int nt = 0; nt < 8; ++nt) {
    uint4 wn[8];
    if (nt < 7) {
#pragma unroll
      for (int kk = 0; kk < 8; ++kk) wn[kk] = mp[((nt + 1) * 8 + kk) * 64];
    }
#pragma unroll
    for (int kk = 0; kk < 8; ++kk) {
      U16x8 bf; bf.u4 = wb[kk];
      acc[0][nt] = __builtin_amdgcn_mfma_f32_16x16x32_bf16(ax[0][kk & 3], bf.v, acc[0][nt], 0, 0, 0);
      acc[1][nt] = __builtin_amdgcn_mfma_f32_16x16x32_bf16(ax[1][kk & 3], bf.v, acc[1][nt], 0, 0, 0);
    }
    if (nt < 7) {
#pragma unroll
      for (int kk = 0; kk < 8; ++kk) wb[kk] = wn[kk];
    }
  }

  // wave-shuffle LayerNorm + store
#pragma unroll
  for (int mt = 0; mt < 2; ++mt) {
#pragma unroll
    for (int r = 0; r < 4; ++r) {
      float s = 0.f, ss = 0.f;
#pragma unroll
      for (int nt = 0; nt < 8; ++nt) { float v = acc[mt][nt][r]; s += v; ss += v * v; }
      s += __shfl_xor(s, 1); ss += __shfl_xor(ss, 1);
      s += __shfl_xor(s, 2); ss += __shfl_xor(ss, 2);
      s += __shfl_xor(s, 4); ss += __shfl_xor(ss, 4);
      s += __shfl_xor(s, 8); ss += __shfl_xor(ss, 8);
      float m = s * (1.0f / 128.0f);
      float var = ss * (1.0f / 128.0f) - m * m;
      float rstd = rsqrtf(var + 1e-5f);
      u16* xop = xo + (rowbase + mt * 16 + quad * 4 + r) * 128 + am;
#pragma unroll
      for (int nt = 0; nt < 8; ++nt)
        xop[nt * 16] = f2us((acc[mt][nt][r] - m) * rstd * gv[nt] + bv[nt]);
    }
  }
}

// ---------------------------------------------------------------------------
// K5 (MFMA): soft MoE + residual. R16 verified-best: R12 structure (2
// m-tiles/wave, full-H LDS, 1-deep weight pipelines, folded gate, Os
// transpose tail) + Hs pitch 280 (aligned b128 a2 reads) + exp2-gelu.
// Out: LOW=im, HIGH=re u32 pack at gidx (verified T2 layout).
// ---------------------------------------------------------------------------
__global__ __launch_bounds__(256) void k5_mfma(
    const u16* __restrict__ xo, const u16* __restrict__ w1s,
    const u16* __restrict__ w2s, const float* __restrict__ w_router,
    const float* __restrict__ x_re, const float* __restrict__ x_im,
    u16* __restrict__ out) {
  __shared__ __align__(16) u16 Hs[128 * 280];   // 71680 B; Os f32[128][129] aliases
  __shared__ float gate_s[128 * 4];
  int tid = threadIdx.x;
  int wave = tid >> 6, lane = tid & 63;
  int quad = lane >> 4, am = lane & 15;
  int rowbase = blockIdx.x * 128 + wave * 32;

  // router gates: lane -> (px = pp*16+am, e=quad); shuffle softmax over quads
  for (int pp = 0; pp < 2; ++pp) {
    int pxl = wave * 32 + pp * 16 + am;
    const uint4* xr = (const uint4*)(xo + (blockIdx.x * 128 + pxl) * 128);
    float acc = 0.f;
    for (int c8 = 0; c8 < 16; ++c8) {
      U16x8 t; t.u4 = xr[c8];
#pragma unroll
      for (int j = 0; j < 8; ++j)
        acc += us2f(t.h[j]) * w_router[(c8 * 8 + j) * 4 + quad];
    }
    float mx = fmaxf(acc, __shfl_xor(acc, 16));
    mx = fmaxf(mx, __shfl_xor(mx, 32));
    float ex = __expf(acc - mx);
    float sm = ex + __shfl_xor(ex, 16);
    sm += __shfl_xor(sm, 32);
    gate_s[pxl * 4 + quad] = ex / sm;
  }

  // A-frags of X, 2 m-tiles (constant across experts)
  bf16x8 ax[2][4];
#pragma unroll
  for (int mt = 0; mt < 2; ++mt) {
    const uint4* ar = (const uint4*)(xo + (rowbase + mt * 16 + am) * 128 + quad * 8);
#pragma unroll
    for (int ks = 0; ks < 4; ++ks) { U16x8 t; t.u4 = ar[ks * 4]; ax[mt][ks] = t.v; }
  }

  // c2[mt][nt] accumulates gated expert outputs across ALL experts
  f32x4 c2[2][8];
#pragma unroll
  for (int mt = 0; mt < 2; ++mt)
#pragma unroll
    for (int nt = 0; nt < 8; ++nt) c2[mt][nt] = (f32x4){0.f, 0.f, 0.f, 0.f};

  // gelu(v)*g = gv - gv*rcp(1 + exp2(v*(GA2+GB2*v^2))), log2e pre-folded:
  // GA2 = 2*0.7978845608*log2e, GB2 = GA2*0.044715
  const float GA2 = 2.3022085f, GB2 = 0.10294348f;

  for (int e = 0; e < 4; ++e) {
    // ---- stage a: H = gelu(X @ W1[e]) * gate  [32 px x 256 hid per wave]
    const uint4* w1p = (const uint4*)w1s + e * 4096 + lane;
    uint4 wb[4];
#pragma unroll
    for (int ks = 0; ks < 4; ++ks) wb[ks] = w1p[ks * 64];
    for (int nt = 0; nt < 16; ++nt) {
      uint4 wn[4];
      if (nt < 15) {
#pragma unroll
        for (int ks = 0; ks < 4; ++ks) wn[ks] = w1p[((nt + 1) * 4 + ks) * 64];
      }
      f32x4 c1a = (f32x4){0.f, 0.f, 0.f, 0.f};
      f32x4 c1b = (f32x4){0.f, 0.f, 0.f, 0.f};
#pragma unroll
      for (int ks = 0; ks < 4; ++ks) {
        U16x8 bf; bf.u4 = wb[ks];
        c1a = __builtin_amdgcn_mfma_f32_16x16x32_bf16(ax[0][ks], bf.v, c1a, 0, 0, 0);
        c1b = __builtin_amdgcn_mfma_f32_16x16x32_bf16(ax[1][ks], bf.v, c1b, 0, 0, 0);
      }
#pragma unroll
      for (int r = 0; r < 4; ++r) {
        float v = c1a[r];
        float gv0 = gate_s[(wave * 32 + quad * 4 + r) * 4 + e] * v;
        float rc = __builtin_amdgcn_rcpf(
            1.0f + __builtin_amdgcn_exp2f(v * (GA2 + GB2 * v * v)));
        Hs[(wave * 32 + quad * 4 + r) * 280 + nt * 16 + am] = f2us(gv0 - gv0 * rc);
        v = c1b[r];
        float gv1 = gate_s[(wave * 32 + 16 + quad * 4 + r) * 4 + e] * v;
        rc = __builtin_amdgcn_rcpf(
            1.0f + __builtin_amdgcn_exp2f(v * (GA2 + GB2 * v * v)));
        Hs[(wave * 32 + 16 + quad * 4 + r) * 280 + nt * 16 + am] = f2us(gv1 - gv1 * rc);
      }
      if (nt < 15) {
#pragma unroll
        for (int ks = 0; ks < 4; ++ks) wb[ks] = wn[ks];
      }
    }
    // ---- stage b: c2 += (g*H) @ W2[e]  [32 px x 128 out per wave]
    const uint4* w2p = (const uint4*)w2s + e * 4096 + lane;
    uint4 wb2[8];
#pragma unroll
    for (int nt = 0; nt < 8; ++nt) wb2[nt] = w2p[(nt * 8) * 64];
    for (int ks = 0; ks < 8; ++ks) {
      uint4 wn2[8];
      if (ks < 7) {
#pragma unroll
        for (int nt = 0; nt < 8; ++nt) wn2[nt] = w2p[(nt * 8 + ks + 1) * 64];
      }
      U16x8 a2[2];
#pragma unroll
      for (int mt = 0; mt < 2; ++mt)
        a2[mt].u4 = *(const uint4*)(Hs + (wave * 32 + mt * 16 + am) * 280 + ks * 32 + quad * 8);
#pragma unroll
      for (int nt = 0; nt < 8; ++nt) {
        U16x8 bf; bf.u4 = wb2[nt];
        c2[0][nt] = __builtin_amdgcn_mfma_f32_16x16x32_bf16(a2[0].v, bf.v, c2[0][nt], 0, 0, 0);
        c2[1][nt] = __builtin_amdgcn_mfma_f32_16x16x32_bf16(a2[1].v, bf.v, c2[1][nt], 0, 0, 0);
      }
      if (ks < 7) {
#pragma unroll
        for (int nt = 0; nt < 8; ++nt) wb2[nt] = wn2[nt];
      }
    }
  }

  // ---- coalesced residual + store via LDS transpose (verified R10/R12) ----
  // Os[d][px]: d in [0,128) (0..63 = re, 64..127 = im), px in [0,128).
  __syncthreads();               // all waves done reading Hs
  float* Os = (float*)Hs;
#pragma unroll
  for (int nt = 0; nt < 4; ++nt)
#pragma unroll
    for (int mt = 0; mt < 2; ++mt)
#pragma unroll
      for (int r = 0; r < 4; ++r) {
        int pxl = wave * 32 + mt * 16 + quad * 4 + r;
        Os[(nt * 16 + am) * 129 + pxl]      = c2[mt][nt][r];      // re
        Os[(64 + nt * 16 + am) * 129 + pxl] = c2[mt][nt + 4][r];  // im
      }
  __syncthreads();
  int nb  = (blockIdx.x * 128) >> 12;      // batch-time index
  int hw0 = (blockIdx.x * 128) & 4095;     // contiguous hw range of this block
#pragma unroll
  for (int k = 0; k < 32; ++k) {
    int flat = tid + k * 256;              // 8192 (d,px) pairs
    int d = flat >> 7, px = flat & 127;
    int gidx = (nb * 64 + d) * 4096 + hw0 + px;
    float rr = x_re[gidx] + Os[d * 129 + px];
    float ii = x_im[gidx] + Os[(64 + d) * 129 + px];
    ((u32*)out)[gidx] = (u32)f2us(ii) | ((u32)f2us(rr) << 16);
  }
}

// ---------------------------------------------------------------------------
extern "C" void kernel_launch(void* const* d_in, const int* in_sizes, int n_in,
                              void* d_out, int out_size, void* d_ws, size_t ws_size,
                              hipStream_t stream) {
  const float* x_re     = (const float*)d_in[0];
  const float* x_im     = (const float*)d_in[1];
  const float* dt       = (const float*)d_in[2];
  const float* ln_s_g   = (const float*)d_in[3];
  const float* ln_s_b   = (const float*)d_in[4];
  const float* conv_w   = (const float*)d_in[5];
  const float* conv_b   = (const float*)d_in[6];
  const float* ln_t_g   = (const float*)d_in[7];
  const float* ln_t_b   = (const float*)d_in[8];
  const float* enc_re   = (const float*)d_in[9];
  const float* enc_im   = (const float*)d_in[10];
  const float* dec_re   = (const float*)d_in[11];
  const float* dec_im   = (const float*)d_in[12];
  const float* alpha    = (const float*)d_in[13];
  const float* omega    = (const float*)d_in[14];
  // 15..20: wg, bg, p_re, p_im, w_drift, b_drift -> dead code in reference
  const float* w_router = (const float*)d_in[21];
  const float* w1       = (const float*)d_in[22];
  const float* w2       = (const float*)d_in[23];
  const float* ns       = (const float*)d_in[24];

  u16*   buf   = (u16*)d_ws;                             // 32 MiB bf16 ping
  u16*   mencs = (u16*)((char*)d_ws + 33554432);         // 32,768 bf16 (hi+lo)
  u16*   mdecs = mencs + 32768;                          // 32,768 bf16 (hi+lo)
  u16*   wcs   = mdecs + 32768;                          // 147,456 bf16
  u16*   w1s   = wcs + 147456;                           // 131,072 bf16
  u16*   w2s   = w1s + 131072;                           // 131,072 bf16
  u16*   outf  = (u16*)d_out;                            // 32 MiB bf16 pong

  k0_prep<<<1856, 256, 0, stream>>>(conv_w, enc_re, enc_im, dec_re, dec_im,
                                    w1, w2, mencs, mdecs, wcs, w1s, w2s);
  k1_spatial_ln<<<2048, 256, 0, stream>>>(x_re, x_im, ln_s_g, ln_s_b, buf);
  k2_mfma<<<2048, 256, 0, stream>>>(buf, wcs, conv_b, mencs, outf);
  k_scan<<<2048, 256, 0, stream>>>(outf, dt, alpha, omega, ns);
  k4_mfma<<<1024, 256, 0, stream>>>(outf, mdecs, ln_t_g, ln_t_b, buf);
  k5_mfma<<<1024, 256, 0, stream>>>(buf, w1s, w2s, w_router, x_re, x_im, outf);
}

// Round 10
// 436.553 us; speedup vs baseline: 1.0656x; 1.0464x over previous
//
#include <hip/hip_runtime.h>
#include <hip/hip_bf16.h>

// Problem dims
#define BB 2
#define TT 16
#define DD 64
#define HH 64
#define WW 64
#define NPIX 131072

// ESTABLISHED (R0-R9, R9 PASSED @ 6288us; prev session best 1320us):
//  - Inputs f32; output bf16 pairs per complex element, LOW half = IM,
//    HIGH half = RE, at u32 index gidx over [B,T,D,H,W].
//  - Fragment layouts (HW-verified): A: m=lane&15, k=(lane>>4)*8+j ;
//    B: n=lane&15, k=(lane>>4)*8+j ; C/D: col=lane&15, row=(lane>>4)*4+reg.
// R10 (PASSED 1297us): k5 coalesced residual tail + fast gelu.
// R11 (PASSED 1025us): k5 2 m-tiles/wave + pipelined frags + folded gate.
// R12 (PASSED 465us): k3/k4 -> MFMA split-bf16, shuffle-LN.
// R13-R15 (k5 regressions, analyzed): reg budget pins k5 at 2 waves/SIMD;
//    forced caps spill; prefetch ILP required. R12 structure best.
// R16 (PASSED 458us): k5 = R12 + aligned Hs 280 + exp2-gelu -> 159us.
// R17 (NEUTRAL): 2-row fused k2+k3 (conv occupancy loss ate the gain).
// R18 (PASSED 456.8us, best): 1-row conv + fused Menc GEMM; k5 160us
//    stable (VALU 42.6%, Mfma 17.7%) -> k5 is VALU-issue-bound.
// R19 (this round): VALU-op surgery, structures untouched:
//  (a) v_cvt_pk_bf16_f32 (HW RNE, 2 vals/op) replaces 4-op f2us where
//      pairs exist: k5 gelu (c1a[r],c1b[r]), k5 tail (cvt_pk(ii,rr) IS
//      the packed output word), k2 both epilogues, k4 LN store.
//  (b) k_scan coefficients (dr,di,fr,fi,sc) are (t,d)-only -> 16KB f32
//      table built in k0_prep (same f32 expr sequence, bit-identical);
//      k_scan loses all expf/cosf/sinf/log1pf (~80 VALU ops/iter -> ~16).
// ws: 32 MiB bf16 ping + split-bf16 Menc/Mdec frags + swizzled weights
//     + scn[16][64] float4 + sct[16] f32 scan tables.

typedef unsigned short u16;
typedef unsigned int u32;
typedef __attribute__((ext_vector_type(8))) short bf16x8;
typedef __attribute__((ext_vector_type(4))) float f32x4;

union U16x8 { uint4 u4; uint2 u2[2]; u16 h[8]; bf16x8 v; };

__device__ __forceinline__ float us2f(u16 u) {
  union { u32 i; float f; } c; c.i = ((u32)u) << 16; return c.f;
}
__device__ __forceinline__ u16 f2us(float f) {
  u32 x = __float_as_uint(f);
  u32 r = x + 0x7fffu + ((x >> 16) & 1u);  // RNE
  return (u16)(r >> 16);
}
// HW RNE pack: dst.lo = bf16(a), dst.hi = bf16(b). 1 VALU op for 2 values.
__device__ __forceinline__ u32 cvtpk(float a, float b) {
  u32 pk;
  asm("v_cvt_pk_bf16_f32 %0, %1, %2" : "=v"(pk) : "v"(a), "v"(b));
  return pk;
}

// ---------------------------------------------------------------------------
// Prep: split-bf16 Menc/Mdec frags + bf16 fragment-swizzled weights +
// scan coefficient tables:
//  mencs/mdecs [nt8][kk8][lane64][8]  (kk = split*4+ks; hi=bf16(M), lo=bf16(M-hi))
//  wcs [tap9][nt8][ks4][lane64][8] ; w1s [e4][nt16][ks4][lane64][8] ;
//  w2s [e4][nt8][ks8][lane64][8]
//  scn[t*64+d] = (dr,di,fr,fi) f32x4 ; sct[t] = 1+ns*sqrt(dt)  (R19)
// ---------------------------------------------------------------------------
__global__ __launch_bounds__(256) void k0_prep(
    const float* __restrict__ conv_w,
    const float* __restrict__ enc_re, const float* __restrict__ enc_im,
    const float* __restrict__ dec_re, const float* __restrict__ dec_im,
    const float* __restrict__ w1, const float* __restrict__ w2,
    const float* __restrict__ dt, const float* __restrict__ alpha,
    const float* __restrict__ omega, const float* __restrict__ ns_p,
    u16* __restrict__ mencs, u16* __restrict__ mdecs,
    u16* __restrict__ wcs, u16* __restrict__ w1s, u16* __restrict__ w2s,
    float4* __restrict__ scn, float* __restrict__ sct) {
  int idx = blockIdx.x * 256 + threadIdx.x;
  if (idx < 65536) {
    int m = idx >> 15;            // 0=enc, 1=dec
    int z = idx & 32767;
    int s = z >> 14;              // 0=hi, 1=lo
    int q = z & 16383;
    int j = q & 7, lane = (q >> 3) & 63, ks = (q >> 9) & 3, nt = (q >> 11) & 7;
    int k = ks * 32 + (lane >> 4) * 8 + j;
    int n = nt * 16 + (lane & 15);
    const float* mre = m ? dec_re : enc_re;
    const float* mim = m ? dec_im : enc_im;
    float v;
    if (k < 64) v = (n < 64) ?  mre[k * 64 + n]        : mim[k * 64 + n - 64];
    else        v = (n < 64) ? -mim[(k - 64) * 64 + n] : mre[(k - 64) * 64 + n - 64];
    u16 hi = f2us(v);
    u16 val = s ? f2us(v - us2f(hi)) : hi;
    u16* dst = m ? mdecs : mencs;
    dst[((nt * 8 + s * 4 + ks) * 64 + lane) * 8 + j] = val;
  } else if (idx < 212992) {
    int z = idx - 65536;
    int j = z & 7, lane = (z >> 3) & 63, ks = (z >> 9) & 3, nt = (z >> 11) & 7, tap = z >> 14;
    int ic = ks * 32 + (lane >> 4) * 8 + j;
    int oc = nt * 16 + (lane & 15);
    wcs[z] = f2us(conv_w[(oc * 128 + ic) * 9 + tap]);
  } else if (idx < 344064) {
    int z = idx - 212992;
    int j = z & 7, lane = (z >> 3) & 63, ks = (z >> 9) & 3, nt = (z >> 11) & 15, e = z >> 15;
    int k = ks * 32 + (lane >> 4) * 8 + j;
    int nn = nt * 16 + (lane & 15);
    w1s[z] = f2us(w1[e * 32768 + k * 256 + nn]);
  } else if (idx < 475136) {
    int z = idx - 344064;
    int j = z & 7, lane = (z >> 3) & 63, ks = (z >> 9) & 7, nt = (z >> 12) & 7, e = z >> 15;
    int k = ks * 32 + (lane >> 4) * 8 + j;
    int nn = nt * 16 + (lane & 15);
    w2s[z] = f2us(w2[e * 32768 + k * 128 + nn]);
  } else if (idx < 476160) {
    // scan coefficient table (same f32 expression sequence as old k_scan)
    int z = idx - 475136;        // 0..1023
    int t = z >> 6, d = z & 63;
    float a = alpha[d];
    float sp = (a > 20.f) ? a : log1pf(expf(a));
    float lr = -sp, li = omega[d];
    float inv_l2 = 1.0f / (lr * lr + li * li);
    float dtv = dt[t];
    float er = expf(lr * dtv);
    float ang = li * dtv;
    float dr = er * cosf(ang), di = er * sinf(ang);
    float fr = ((dr - 1.f) * lr + di * li) * inv_l2;
    float fi = (di * lr - (dr - 1.f) * li) * inv_l2;
    scn[z] = make_float4(dr, di, fr, fi);
  } else if (idx < 476176) {
    int t = idx - 476160;
    sct[t] = 1.0f + ns_p[0] * sqrtf(dt[t]);
  }
}

// ---------------------------------------------------------------------------
// K1: spatial LayerNorm over channels, f32 NCHW(re|im planes) -> bf16
// channels-last. (unchanged from verified R9; memory-bound, f2us kept)
// ---------------------------------------------------------------------------
__global__ __launch_bounds__(256) void k1_spatial_ln(
    const float* __restrict__ x_re, const float* __restrict__ x_im,
    const float* __restrict__ g, const float* __restrict__ b,
    u16* __restrict__ xn) {
  __shared__ float tile[64 * 129];
  __shared__ float meanA[64], rstdA[64];
  int n = blockIdx.x >> 6, h = blockIdx.x & 63;
  int tid = threadIdx.x;
  for (int k = 0; k < 32; ++k) {
    int flat = tid + k * 256;
    int c = flat >> 6, w = flat & 63;
    float v = (c < 64) ? x_re[n * 262144 + c * 4096 + h * 64 + w]
                       : x_im[n * 262144 + (c - 64) * 4096 + h * 64 + w];
    tile[w * 129 + c] = v;
  }
  __syncthreads();
  int p = tid >> 2, q = tid & 3;
  float s = 0.f, ss = 0.f;
  for (int c = q * 32; c < q * 32 + 32; ++c) {
    float v = tile[p * 129 + c];
    s += v; ss += v * v;
  }
  s += __shfl_xor(s, 1); ss += __shfl_xor(ss, 1);
  s += __shfl_xor(s, 2); ss += __shfl_xor(ss, 2);
  if (q == 0) {
    float m = s * (1.0f / 128.0f);
    float var = ss * (1.0f / 128.0f) - m * m;
    meanA[p] = m; rstdA[p] = rsqrtf(var + 1e-5f);
  }
  __syncthreads();
  int rowbase = (n * 4096 + h * 64) * 128;
  for (int k = 0; k < 32; ++k) {
    int flat = tid + k * 256;
    int pp = flat >> 7, c = flat & 127;
    float v = (tile[pp * 129 + c] - meanA[pp]) * rstdA[pp] * g[c] + b[c];
    xn[rowbase + flat] = f2us(v);
  }
}

// ---------------------------------------------------------------------------
// K2 (MFMA, R18 structure): 3x3 SAME conv + FUSED Menc GEMM, 1-ROW blocks.
// R19: epilogue conversions via cvt_pk pairs (r 0/1, 2/3 for Cs; ca/cb for
// xs store). Math identical (HW RNE == f2us RNE).
// ---------------------------------------------------------------------------
__global__ __launch_bounds__(256) void k2_mfma(
    const u16* __restrict__ xn, const u16* __restrict__ wcs,
    const float* __restrict__ conv_b, const u16* __restrict__ ms,
    u16* __restrict__ xs) {
  __shared__ __align__(16) u16 Xs[3 * 66 * 132];   // 52272 B; Cs[64][136] aliases
  int tid = threadIdx.x;
  int wave = tid >> 6, lane = tid & 63;
  int quad = lane >> 4, am = lane & 15;
  int n = blockIdx.x >> 6, h = blockIdx.x & 63;

  for (int dh = 0; dh < 3; ++dh) {
    int hs = h + dh - 1;
    bool valid = (hs >= 0) && (hs < 64);
    const u16* src = xn + (n * 4096 + hs * 64) * 128;
    for (int c = 0; c < 4; ++c) {
      int f8 = tid + c * 256;            // 1024 chunks of 8 bf16
      int px = f8 >> 4, ch = (f8 & 15) * 8;
      uint2 lo = make_uint2(0, 0), hi = make_uint2(0, 0);
      if (valid) {
        const uint2* s2 = (const uint2*)(src + px * 128 + ch);
        lo = s2[0]; hi = s2[1];
      }
      u16* dst = Xs + (dh * 66 + px + 1) * 132 + ch;
      *(uint2*)dst = lo;
      *(uint2*)(dst + 4) = hi;
    }
  }
  for (int z = tid; z < 792; z += 256) {   // zero px=-1 / px=64 halos
    int dh = z / 264, r = z % 264;
    int px = (r < 132) ? 0 : 65;
    Xs[(dh * 66 + px) * 132 + (r % 132)] = 0;
  }
  __syncthreads();

  f32x4 acc[8];
#pragma unroll
  for (int nt = 0; nt < 8; ++nt) {
    float bv = conv_b[nt * 16 + am];
    acc[nt] = (f32x4){bv, bv, bv, bv};
  }
  int mt = wave;
  for (int tap = 0; tap < 9; ++tap) {
    int dh = tap / 3, dw = tap % 3;      // dw: 0,1,2 -> shift -1,0,+1 (halo idx)
    const u16* arow = Xs + (dh * 66 + mt * 16 + am + dw) * 132 + quad * 8;
    bf16x8 a[4];
#pragma unroll
    for (int ks = 0; ks < 4; ++ks) {
      U16x8 t;
      t.u2[0] = *(const uint2*)(arow + ks * 32);
      t.u2[1] = *(const uint2*)(arow + ks * 32 + 4);
      a[ks] = t.v;
    }
    const uint4* wp = (const uint4*)wcs + tap * 2048 + lane;
    uint4 wb[4];
#pragma unroll
    for (int ks = 0; ks < 4; ++ks) wb[ks] = wp[ks * 64];
    for (int nt = 0; nt < 8; ++nt) {
      uint4 wn[4];
      if (nt < 7) {
#pragma unroll
        for (int ks = 0; ks < 4; ++ks) wn[ks] = wp[((nt + 1) * 4 + ks) * 64];
      }
#pragma unroll
      for (int ks = 0; ks < 4; ++ks) {
        U16x8 bf; bf.u4 = wb[ks];
        acc[nt] = __builtin_amdgcn_mfma_f32_16x16x32_bf16(a[ks], bf.v, acc[nt], 0, 0, 0);
      }
      if (nt < 7) {
#pragma unroll
        for (int ks = 0; ks < 4; ++ks) wb[ks] = wn[ks];
      }
    }
  }

  // ---- stage conv result to Cs (channel transpose), cvt_pk pairs (R19)
  __syncthreads();               // all conv A-reads from Xs complete
  u16* Cs = Xs;                  // [64 px][pitch 136] bf16 = 17408 B
#pragma unroll
  for (int nt = 0; nt < 8; ++nt)
#pragma unroll
    for (int rp = 0; rp < 2; ++rp) {
      u32 pk = cvtpk(acc[nt][2 * rp], acc[nt][2 * rp + 1]);
      Cs[(wave * 16 + quad * 4 + 2 * rp) * 136 + nt * 16 + am]     = (u16)pk;
      Cs[(wave * 16 + quad * 4 + 2 * rp + 1) * 136 + nt * 16 + am] = (u16)(pk >> 16);
    }
  __syncthreads();

  // ---- fused Menc GEMM (k3 verbatim math: split-bf16, kk 0..7 ascending)
  bf16x8 a2[4];
  {
    const u16* crow = Cs + (wave * 16 + am) * 136;
#pragma unroll
    for (int ks = 0; ks < 4; ++ks) {
      U16x8 t; t.u4 = *(const uint4*)(crow + ks * 32 + quad * 8);
      a2[ks] = t.v;
    }
  }
  const uint4* mp = (const uint4*)ms + lane;
  int rowg = n * 4096 + h * 64 + wave * 16;
  for (int p = 0; p < 4; ++p) {            // nt-pairs: 2 indep chains of ILP
    f32x4 ca = (f32x4){0.f, 0.f, 0.f, 0.f};
    f32x4 cb = (f32x4){0.f, 0.f, 0.f, 0.f};
#pragma unroll
    for (int kk = 0; kk < 8; ++kk) {
      U16x8 b0; b0.u4 = mp[((2 * p) * 8 + kk) * 64];
      U16x8 b1; b1.u4 = mp[((2 * p + 1) * 8 + kk) * 64];
      ca = __builtin_amdgcn_mfma_f32_16x16x32_bf16(a2[kk & 3], b0.v, ca, 0, 0, 0);
      cb = __builtin_amdgcn_mfma_f32_16x16x32_bf16(a2[kk & 3], b1.v, cb, 0, 0, 0);
    }
#pragma unroll
    for (int r = 0; r < 4; ++r) {
      u32 pk = cvtpk(ca[r], cb[r]);
      xs[(rowg + quad * 4 + r) * 128 + (2 * p) * 16 + am]     = (u16)pk;
      xs[(rowg + quad * 4 + r) * 128 + (2 * p + 1) * 16 + am] = (u16)(pk >> 16);
    }
  }
}

// ---------------------------------------------------------------------------
// K_scan (R19): temporal ZOH scan T=16 in place, coefficients from the
// precomputed scn/sct tables (bit-identical f32 values; all transcendentals
// moved to k0_prep). Stores via cvt_pk.
// ---------------------------------------------------------------------------
__global__ __launch_bounds__(256) void k_scan(
    u16* __restrict__ u, const float4* __restrict__ scn,
    const float* __restrict__ sct) {
  int flat = blockIdx.x * 256 + threadIdx.x;
  int d = flat & 63;
  int hw = (flat >> 6) & 4095;
  int b = flat >> 18;
  float yr = 0.f, yi = 0.f;
  const int stride = 4096 * 128;
  int base0 = b * 16 * stride + hw * 128 + d;
  for (int t = 0; t < 16; ++t) {
    float4 c = scn[t * 64 + d];            // dr, di, fr, fi
    int idx = base0 + t * stride;
    float ur = us2f(u[idx]), ui = us2f(u[idx + 64]);
    float usr = ur * c.z - ui * c.w;
    float usi = ur * c.w + ui * c.z;
    float nyr = c.x * yr - c.y * yi + usr;
    float nyi = c.x * yi + c.y * yr + usi;
    yr = nyr; yi = nyi;
    float sc = sct[t];
    u32 pk = cvtpk(yr * sc, yi * sc);
    u[idx]      = (u16)pk;
    u[idx + 64] = (u16)(pk >> 16);
  }
}

// ---------------------------------------------------------------------------
// K4 (MFMA, R12 structure): xo <- LN(U @ Mdec), split-bf16 weights +
// wave-shuffle LayerNorm. R19: store conversions via cvt_pk nt-pairs.
// ---------------------------------------------------------------------------
__global__ __launch_bounds__(256) void k4_mfma(
    const u16* __restrict__ U, const u16* __restrict__ ms,
    const float* __restrict__ g, const float* __restrict__ bb,
    u16* __restrict__ xo) {
  int tid = threadIdx.x;
  int wave = tid >> 6, lane = tid & 63;
  int quad = lane >> 4, am = lane & 15;
  int rowbase = blockIdx.x * 128 + wave * 32;

  bf16x8 ax[2][4];
#pragma unroll
  for (int mt = 0; mt < 2; ++mt) {
    const uint4* ar = (const uint4*)(U + (rowbase + mt * 16 + am) * 128 + quad * 8);
#pragma unroll
    for (int ks = 0; ks < 4; ++ks) { U16x8 t; t.u4 = ar[ks * 4]; ax[mt][ks] = t.v; }
  }
  float gv[8], bv[8];
#pragma unroll
  for (int nt = 0; nt < 8; ++nt) { gv[nt] = g[nt * 16 + am]; bv[nt] = bb[nt * 16 + am]; }

  const uint4* mp = (const uint4*)ms + lane;
  f32x4 acc[2][8];
#pragma unroll
  for (int mt = 0; mt < 2; ++mt)
#pragma unroll
    for (int nt = 0; nt < 8; ++nt) acc[mt][nt] = (f32x4){0.f, 0.f, 0.f, 0.f};

  uint4 wb[8];
#pragma unroll
  for (int kk = 0; kk < 8; ++kk) wb[kk] = mp[kk * 64];
  for (int nt = 0; nt < 8; ++nt) {
    uint4 wn[8];
    if (nt < 7) {
#pragma unroll
      for (int kk = 0; kk < 8; ++kk) wn[kk] = mp[((nt + 1) * 8 + kk) * 64];
    }
#pragma unroll
    for (int kk = 0; kk < 8; ++kk) {
      U16x8 bf; bf.u4 = wb[kk];
      acc[0][nt] = __builtin_amdgcn_mfma_f32_16x16x32_bf16(ax[0][kk & 3], bf.v, acc[0][nt], 0, 0, 0);
      acc[1][nt] = __builtin_amdgcn_mfma_f32_16x16x32_bf16(ax[1][kk & 3], bf.v, acc[1][nt], 0, 0, 0);
    }
    if (nt < 7) {
#pragma unroll
      for (int kk = 0; kk < 8; ++kk) wb[kk] = wn[kk];
    }
  }

  // wave-shuffle LayerNorm + store (cvt_pk nt-pairs)
#pragma unroll
  for (int mt = 0; mt < 2; ++mt) {
#pragma unroll
    for (int r = 0; r < 4; ++r) {
      float s = 0.f, ss = 0.f;
#pragma unroll
      for (int nt = 0; nt < 8; ++nt) { float v = acc[mt][nt][r]; s += v; ss += v * v; }
      s += __shfl_xor(s, 1); ss += __shfl_xor(ss, 1);
      s += __shfl_xor(s, 2); ss += __shfl_xor(ss, 2);
      s += __shfl_xor(s, 4); ss += __shfl_xor(ss, 4);
      s += __shfl_xor(s, 8); ss += __shfl_xor(ss, 8);
      float m = s * (1.0f / 128.0f);
      float var = ss * (1.0f / 128.0f) - m * m;
      float rstd = rsqrtf(var + 1e-5f);
      u16* xop = xo + (rowbase + mt * 16 + quad * 4 + r) * 128 + am;
#pragma unroll
      for (int n2 = 0; n2 < 4; ++n2) {
        float v0 = (acc[mt][2 * n2][r] - m) * rstd * gv[2 * n2] + bv[2 * n2];
        float v1 = (acc[mt][2 * n2 + 1][r] - m) * rstd * gv[2 * n2 + 1] + bv[2 * n2 + 1];
        u32 pk = cvtpk(v0, v1);
        xop[(2 * n2) * 16]     = (u16)pk;
        xop[(2 * n2 + 1) * 16] = (u16)(pk >> 16);
      }
    }
  }
}

// ---------------------------------------------------------------------------
// K5 (MFMA): soft MoE + residual. R16 verified-best structure (R12 + Hs
// pitch 280 + exp2-gelu). R19: gelu pair conversions via cvt_pk
// (c1a[r],c1b[r] -> one op), tail cvt_pk(ii,rr) IS the packed output u32.
// Out: LOW=im, HIGH=re u32 pack at gidx (verified T2 layout).
// ---------------------------------------------------------------------------
__global__ __launch_bounds__(256) void k5_mfma(
    const u16* __restrict__ xo, const u16* __restrict__ w1s,
    const u16* __restrict__ w2s, const float* __restrict__ w_router,
    const float* __restrict__ x_re, const float* __restrict__ x_im,
    u16* __restrict__ out) {
  __shared__ __align__(16) u16 Hs[128 * 280];   // 71680 B; Os f32[128][129] aliases
  __shared__ float gate_s[128 * 4];
  int tid = threadIdx.x;
  int wave = tid >> 6, lane = tid & 63;
  int quad = lane >> 4, am = lane & 15;
  int rowbase = blockIdx.x * 128 + wave * 32;

  // router gates: lane -> (px = pp*16+am, e=quad); shuffle softmax over quads
  for (int pp = 0; pp < 2; ++pp) {
    int pxl = wave * 32 + pp * 16 + am;
    const uint4* xr = (const uint4*)(xo + (blockIdx.x * 128 + pxl) * 128);
    float acc = 0.f;
    for (int c8 = 0; c8 < 16; ++c8) {
      U16x8 t; t.u4 = xr[c8];
#pragma unroll
      for (int j = 0; j < 8; ++j)
        acc += us2f(t.h[j]) * w_router[(c8 * 8 + j) * 4 + quad];
    }
    float mx = fmaxf(acc, __shfl_xor(acc, 16));
    mx = fmaxf(mx, __shfl_xor(mx, 32));
    float ex = __expf(acc - mx);
    float sm = ex + __shfl_xor(ex, 16);
    sm += __shfl_xor(sm, 32);
    gate_s[pxl * 4 + quad] = ex / sm;
  }

  // A-frags of X, 2 m-tiles (constant across experts)
  bf16x8 ax[2][4];
#pragma unroll
  for (int mt = 0; mt < 2; ++mt) {
    const uint4* ar = (const uint4*)(xo + (rowbase + mt * 16 + am) * 128 + quad * 8);
#pragma unroll
    for (int ks = 0; ks < 4; ++ks) { U16x8 t; t.u4 = ar[ks * 4]; ax[mt][ks] = t.v; }
  }

  // c2[mt][nt] accumulates gated expert outputs across ALL experts
  f32x4 c2[2][8];
#pragma unroll
  for (int mt = 0; mt < 2; ++mt)
#pragma unroll
    for (int nt = 0; nt < 8; ++nt) c2[mt][nt] = (f32x4){0.f, 0.f, 0.f, 0.f};

  // gelu(v)*g = gv - gv*rcp(1 + exp2(v*(GA2+GB2*v^2))), log2e pre-folded:
  // GA2 = 2*0.7978845608*log2e, GB2 = GA2*0.044715
  const float GA2 = 2.3022085f, GB2 = 0.10294348f;

  for (int e = 0; e < 4; ++e) {
    // ---- stage a: H = gelu(X @ W1[e]) * gate  [32 px x 256 hid per wave]
    const uint4* w1p = (const uint4*)w1s + e * 4096 + lane;
    uint4 wb[4];
#pragma unroll
    for (int ks = 0; ks < 4; ++ks) wb[ks] = w1p[ks * 64];
    for (int nt = 0; nt < 16; ++nt) {
      uint4 wn[4];
      if (nt < 15) {
#pragma unroll
        for (int ks = 0; ks < 4; ++ks) wn[ks] = w1p[((nt + 1) * 4 + ks) * 64];
      }
      f32x4 c1a = (f32x4){0.f, 0.f, 0.f, 0.f};
      f32x4 c1b = (f32x4){0.f, 0.f, 0.f, 0.f};
#pragma unroll
      for (int ks = 0; ks < 4; ++ks) {
        U16x8 bf; bf.u4 = wb[ks];
        c1a = __builtin_amdgcn_mfma_f32_16x16x32_bf16(ax[0][ks], bf.v, c1a, 0, 0, 0);
        c1b = __builtin_amdgcn_mfma_f32_16x16x32_bf16(ax[1][ks], bf.v, c1b, 0, 0, 0);
      }
#pragma unroll
      for (int r = 0; r < 4; ++r) {
        float v = c1a[r];
        float gv0 = gate_s[(wave * 32 + quad * 4 + r) * 4 + e] * v;
        float rc = __builtin_amdgcn_rcpf(
            1.0f + __builtin_amdgcn_exp2f(v * (GA2 + GB2 * v * v)));
        float h0 = gv0 - gv0 * rc;
        v = c1b[r];
        float gv1 = gate_s[(wave * 32 + 16 + quad * 4 + r) * 4 + e] * v;
        rc = __builtin_amdgcn_rcpf(
            1.0f + __builtin_amdgcn_exp2f(v * (GA2 + GB2 * v * v)));
        float h1 = gv1 - gv1 * rc;
        u32 pk = cvtpk(h0, h1);
        Hs[(wave * 32 + quad * 4 + r) * 280 + nt * 16 + am]      = (u16)pk;
        Hs[(wave * 32 + 16 + quad * 4 + r) * 280 + nt * 16 + am] = (u16)(pk >> 16);
      }
      if (nt < 15) {
#pragma unroll
        for (int ks = 0; ks < 4; ++ks) wb[ks] = wn[ks];
      }
    }
    // ---- stage b: c2 += (g*H) @ W2[e]  [32 px x 128 out per wave]
    const uint4* w2p = (const uint4*)w2s + e * 4096 + lane;
    uint4 wb2[8];
#pragma unroll
    for (int nt = 0; nt < 8; ++nt) wb2[nt] = w2p[(nt * 8) * 64];
    for (int ks = 0; ks < 8; ++ks) {
      uint4 wn2[8];
      if (ks < 7) {
#pragma unroll
        for (int nt = 0; nt < 8; ++nt) wn2[nt] = w2p[(nt * 8 + ks + 1) * 64];
      }
      U16x8 a2[2];
#pragma unroll
      for (int mt = 0; mt < 2; ++mt)
        a2[mt].u4 = *(const uint4*)(Hs + (wave * 32 + mt * 16 + am) * 280 + ks * 32 + quad * 8);
#pragma unroll
      for (int nt = 0; nt < 8; ++nt) {
        U16x8 bf; bf.u4 = wb2[nt];
        c2[0][nt] = __builtin_amdgcn_mfma_f32_16x16x32_bf16(a2[0].v, bf.v, c2[0][nt], 0, 0, 0);
        c2[1][nt] = __builtin_amdgcn_mfma_f32_16x16x32_bf16(a2[1].v, bf.v, c2[1][nt], 0, 0, 0);
      }
      if (ks < 7) {
#pragma unroll
        for (int nt = 0; nt < 8; ++nt) wb2[nt] = wn2[nt];
      }
    }
  }

  // ---- coalesced residual + store via LDS transpose (verified R10/R12) ----
  // Os[d][px]: d in [0,128) (0..63 = re, 64..127 = im), px in [0,128).
  __syncthreads();               // all waves done reading Hs
  float* Os = (float*)Hs;
#pragma unroll
  for (int nt = 0; nt < 4; ++nt)
#pragma unroll
    for (int mt = 0; mt < 2; ++mt)
#pragma unroll
      for (int r = 0; r < 4; ++r) {
        int pxl = wave * 32 + mt * 16 + quad * 4 + r;
        Os[(nt * 16 + am) * 129 + pxl]      = c2[mt][nt][r];      // re
        Os[(64 + nt * 16 + am) * 129 + pxl] = c2[mt][nt + 4][r];  // im
      }
  __syncthreads();
  int nb  = (blockIdx.x * 128) >> 12;      // batch-time index
  int hw0 = (blockIdx.x * 128) & 4095;     // contiguous hw range of this block
#pragma unroll
  for (int k = 0; k < 32; ++k) {
    int flat = tid + k * 256;              // 8192 (d,px) pairs
    int d = flat >> 7, px = flat & 127;
    int gidx = (nb * 64 + d) * 4096 + hw0 + px;
    float rr = x_re[gidx] + Os[d * 129 + px];
    float ii = x_im[gidx] + Os[(64 + d) * 129 + px];
    ((u32*)out)[gidx] = cvtpk(ii, rr);     // lo=im, hi=re (verified layout)
  }
}

// ---------------------------------------------------------------------------
extern "C" void kernel_launch(void* const* d_in, const int* in_sizes, int n_in,
                              void* d_out, int out_size, void* d_ws, size_t ws_size,
                              hipStream_t stream) {
  const float* x_re     = (const float*)d_in[0];
  const float* x_im     = (const float*)d_in[1];
  const float* dt       = (const float*)d_in[2];
  const float* ln_s_g   = (const float*)d_in[3];
  const float* ln_s_b   = (const float*)d_in[4];
  const float* conv_w   = (const float*)d_in[5];
  const float* conv_b   = (const float*)d_in[6];
  const float* ln_t_g   = (const float*)d_in[7];
  const float* ln_t_b   = (const float*)d_in[8];
  const float* enc_re   = (const float*)d_in[9];
  const float* enc_im   = (const float*)d_in[10];
  const float* dec_re   = (const float*)d_in[11];
  const float* dec_im   = (const float*)d_in[12];
  const float* alpha    = (const float*)d_in[13];
  const float* omega    = (const float*)d_in[14];
  // 15..20: wg, bg, p_re, p_im, w_drift, b_drift -> dead code in reference
  const float* w_router = (const float*)d_in[21];
  const float* w1       = (const float*)d_in[22];
  const float* w2       = (const float*)d_in[23];
  const float* ns       = (const float*)d_in[24];

  u16*   buf   = (u16*)d_ws;                             // 32 MiB bf16 ping
  u16*   mencs = (u16*)((char*)d_ws + 33554432);         // 32,768 bf16 (hi+lo)
  u16*   mdecs = mencs + 32768;                          // 32,768 bf16 (hi+lo)
  u16*   wcs   = mdecs + 32768;                          // 147,456 bf16
  u16*   w1s   = wcs + 147456;                           // 131,072 bf16
  u16*   w2s   = w1s + 131072;                           // 131,072 bf16
  float4* scn  = (float4*)(w2s + 131072);                // 1024 float4 (16KB)
  float* sct   = (float*)(scn + 1024);                   // 16 f32
  u16*   outf  = (u16*)d_out;                            // 32 MiB bf16 pong

  k0_prep<<<1861, 256, 0, stream>>>(conv_w, enc_re, enc_im, dec_re, dec_im,
                                    w1, w2, dt, alpha, omega, ns,
                                    mencs, mdecs, wcs, w1s, w2s, scn, sct);
  k1_spatial_ln<<<2048, 256, 0, stream>>>(x_re, x_im, ln_s_g, ln_s_b, buf);
  k2_mfma<<<2048, 256, 0, stream>>>(buf, wcs, conv_b, mencs, outf);
  k_scan<<<2048, 256, 0, stream>>>(outf, scn, sct);
  k4_mfma<<<1024, 256, 0, stream>>>(outf, mdecs, ln_t_g, ln_t_b, buf);
  k5_mfma<<<1024, 256, 0, stream>>>(buf, w1s, w2s, w_router, x_re, x_im, outf);
}

// Round 11
// 434.778 us; speedup vs baseline: 1.0700x; 1.0041x over previous
//
#include <hip/hip_runtime.h>
#include <hip/hip_bf16.h>

// Problem dims
#define BB 2
#define TT 16
#define DD 64
#define HH 64
#define WW 64
#define NPIX 131072

// ESTABLISHED (R0-R9, R9 PASSED @ 6288us; prev session best 1320us):
//  - Inputs f32; output bf16 pairs per complex element, LOW half = IM,
//    HIGH half = RE, at u32 index gidx over [B,T,D,H,W].
//  - Fragment layouts (HW-verified): A: m=lane&15, k=(lane>>4)*8+j ;
//    B: n=lane&15, k=(lane>>4)*8+j ; C/D: col=lane&15, row=(lane>>4)*4+reg.
// R10-R12: 1297 -> 1025 -> 465us (k5 restructure; k3/k4 MFMA split-bf16).
// R13-R15 (k5 regressions, analyzed): reg budget pins k5 at 2 waves/SIMD;
//    forced caps spill; prefetch ILP required. R12 structure best.
// R16 (PASSED 458us): k5 = R12 + aligned Hs 280 + exp2-gelu -> 159us
//    (re-measured 159.4-160.2 across R16/R17/R18 — the verified k5).
// R17 (NEUTRAL): 2-row fused k2+k3 (conv occupancy loss ate the gain).
// R18 (PASSED 456.8us): 1-row conv + fused Menc GEMM.
// R19 (PASSED 436.6us): scan-coeff table + cvt_pk epilogues: non-k5
//    residue 297->263us (KEPT). BUT k5 gelu-loop cvt_pk REGRESSED k5
//    159.8->173.4 (inline asm defeats scheduling in the pipelined MFMA
//    loop — the documented m240 effect; epilogue uses are fine).
// R20 (this round): k5 reverted to R16-verbatim (f2us in gelu + tail);
//    k2/k4/k_scan keep R19 cvt_pk epilogues; scan table kept.
// ws: 32 MiB bf16 ping + split-bf16 Menc/Mdec frags + swizzled weights
//     + scn[16][64] float4 + sct[16] f32 scan tables.

typedef unsigned short u16;
typedef unsigned int u32;
typedef __attribute__((ext_vector_type(8))) short bf16x8;
typedef __attribute__((ext_vector_type(4))) float f32x4;

union U16x8 { uint4 u4; uint2 u2[2]; u16 h[8]; bf16x8 v; };

__device__ __forceinline__ float us2f(u16 u) {
  union { u32 i; float f; } c; c.i = ((u32)u) << 16; return c.f;
}
__device__ __forceinline__ u16 f2us(float f) {
  u32 x = __float_as_uint(f);
  u32 r = x + 0x7fffu + ((x >> 16) & 1u);  // RNE
  return (u16)(r >> 16);
}
// HW RNE pack: dst.lo = bf16(a), dst.hi = bf16(b). 1 VALU op for 2 values.
// ONLY for epilogues/latency-bound loops — in pipelined MFMA loops the
// inline asm defeats compiler scheduling (R19 measured: k5 +14us).
__device__ __forceinline__ u32 cvtpk(float a, float b) {
  u32 pk;
  asm("v_cvt_pk_bf16_f32 %0, %1, %2" : "=v"(pk) : "v"(a), "v"(b));
  return pk;
}

// ---------------------------------------------------------------------------
// Prep: split-bf16 Menc/Mdec frags + bf16 fragment-swizzled weights +
// scan coefficient tables:
//  mencs/mdecs [nt8][kk8][lane64][8]  (kk = split*4+ks; hi=bf16(M), lo=bf16(M-hi))
//  wcs [tap9][nt8][ks4][lane64][8] ; w1s [e4][nt16][ks4][lane64][8] ;
//  w2s [e4][nt8][ks8][lane64][8]
//  scn[t*64+d] = (dr,di,fr,fi) f32x4 ; sct[t] = 1+ns*sqrt(dt)  (R19)
// ---------------------------------------------------------------------------
__global__ __launch_bounds__(256) void k0_prep(
    const float* __restrict__ conv_w,
    const float* __restrict__ enc_re, const float* __restrict__ enc_im,
    const float* __restrict__ dec_re, const float* __restrict__ dec_im,
    const float* __restrict__ w1, const float* __restrict__ w2,
    const float* __restrict__ dt, const float* __restrict__ alpha,
    const float* __restrict__ omega, const float* __restrict__ ns_p,
    u16* __restrict__ mencs, u16* __restrict__ mdecs,
    u16* __restrict__ wcs, u16* __restrict__ w1s, u16* __restrict__ w2s,
    float4* __restrict__ scn, float* __restrict__ sct) {
  int idx = blockIdx.x * 256 + threadIdx.x;
  if (idx < 65536) {
    int m = idx >> 15;            // 0=enc, 1=dec
    int z = idx & 32767;
    int s = z >> 14;              // 0=hi, 1=lo
    int q = z & 16383;
    int j = q & 7, lane = (q >> 3) & 63, ks = (q >> 9) & 3, nt = (q >> 11) & 7;
    int k = ks * 32 + (lane >> 4) * 8 + j;
    int n = nt * 16 + (lane & 15);
    const float* mre = m ? dec_re : enc_re;
    const float* mim = m ? dec_im : enc_im;
    float v;
    if (k < 64) v = (n < 64) ?  mre[k * 64 + n]        : mim[k * 64 + n - 64];
    else        v = (n < 64) ? -mim[(k - 64) * 64 + n] : mre[(k - 64) * 64 + n - 64];
    u16 hi = f2us(v);
    u16 val = s ? f2us(v - us2f(hi)) : hi;
    u16* dst = m ? mdecs : mencs;
    dst[((nt * 8 + s * 4 + ks) * 64 + lane) * 8 + j] = val;
  } else if (idx < 212992) {
    int z = idx - 65536;
    int j = z & 7, lane = (z >> 3) & 63, ks = (z >> 9) & 3, nt = (z >> 11) & 7, tap = z >> 14;
    int ic = ks * 32 + (lane >> 4) * 8 + j;
    int oc = nt * 16 + (lane & 15);
    wcs[z] = f2us(conv_w[(oc * 128 + ic) * 9 + tap]);
  } else if (idx < 344064) {
    int z = idx - 212992;
    int j = z & 7, lane = (z >> 3) & 63, ks = (z >> 9) & 3, nt = (z >> 11) & 15, e = z >> 15;
    int k = ks * 32 + (lane >> 4) * 8 + j;
    int nn = nt * 16 + (lane & 15);
    w1s[z] = f2us(w1[e * 32768 + k * 256 + nn]);
  } else if (idx < 475136) {
    int z = idx - 344064;
    int j = z & 7, lane = (z >> 3) & 63, ks = (z >> 9) & 7, nt = (z >> 12) & 7, e = z >> 15;
    int k = ks * 32 + (lane >> 4) * 8 + j;
    int nn = nt * 16 + (lane & 15);
    w2s[z] = f2us(w2[e * 32768 + k * 128 + nn]);
  } else if (idx < 476160) {
    // scan coefficient table (same f32 expression sequence as old k_scan)
    int z = idx - 475136;        // 0..1023
    int t = z >> 6, d = z & 63;
    float a = alpha[d];
    float sp = (a > 20.f) ? a : log1pf(expf(a));
    float lr = -sp, li = omega[d];
    float inv_l2 = 1.0f / (lr * lr + li * li);
    float dtv = dt[t];
    float er = expf(lr * dtv);
    float ang = li * dtv;
    float dr = er * cosf(ang), di = er * sinf(ang);
    float fr = ((dr - 1.f) * lr + di * li) * inv_l2;
    float fi = (di * lr - (dr - 1.f) * li) * inv_l2;
    scn[z] = make_float4(dr, di, fr, fi);
  } else if (idx < 476176) {
    int t = idx - 476160;
    sct[t] = 1.0f + ns_p[0] * sqrtf(dt[t]);
  }
}

// ---------------------------------------------------------------------------
// K1: spatial LayerNorm over channels, f32 NCHW(re|im planes) -> bf16
// channels-last. (unchanged from verified R9; memory-bound, f2us kept)
// ---------------------------------------------------------------------------
__global__ __launch_bounds__(256) void k1_spatial_ln(
    const float* __restrict__ x_re, const float* __restrict__ x_im,
    const float* __restrict__ g, const float* __restrict__ b,
    u16* __restrict__ xn) {
  __shared__ float tile[64 * 129];
  __shared__ float meanA[64], rstdA[64];
  int n = blockIdx.x >> 6, h = blockIdx.x & 63;
  int tid = threadIdx.x;
  for (int k = 0; k < 32; ++k) {
    int flat = tid + k * 256;
    int c = flat >> 6, w = flat & 63;
    float v = (c < 64) ? x_re[n * 262144 + c * 4096 + h * 64 + w]
                       : x_im[n * 262144 + (c - 64) * 4096 + h * 64 + w];
    tile[w * 129 + c] = v;
  }
  __syncthreads();
  int p = tid >> 2, q = tid & 3;
  float s = 0.f, ss = 0.f;
  for (int c = q * 32; c < q * 32 + 32; ++c) {
    float v = tile[p * 129 + c];
    s += v; ss += v * v;
  }
  s += __shfl_xor(s, 1); ss += __shfl_xor(ss, 1);
  s += __shfl_xor(s, 2); ss += __shfl_xor(ss, 2);
  if (q == 0) {
    float m = s * (1.0f / 128.0f);
    float var = ss * (1.0f / 128.0f) - m * m;
    meanA[p] = m; rstdA[p] = rsqrtf(var + 1e-5f);
  }
  __syncthreads();
  int rowbase = (n * 4096 + h * 64) * 128;
  for (int k = 0; k < 32; ++k) {
    int flat = tid + k * 256;
    int pp = flat >> 7, c = flat & 127;
    float v = (tile[pp * 129 + c] - meanA[pp]) * rstdA[pp] * g[c] + b[c];
    xn[rowbase + flat] = f2us(v);
  }
}

// ---------------------------------------------------------------------------
// K2 (MFMA, R18 structure): 3x3 SAME conv + FUSED Menc GEMM, 1-ROW blocks.
// R19 (kept): epilogue conversions via cvt_pk pairs. Math identical.
// ---------------------------------------------------------------------------
__global__ __launch_bounds__(256) void k2_mfma(
    const u16* __restrict__ xn, const u16* __restrict__ wcs,
    const float* __restrict__ conv_b, const u16* __restrict__ ms,
    u16* __restrict__ xs) {
  __shared__ __align__(16) u16 Xs[3 * 66 * 132];   // 52272 B; Cs[64][136] aliases
  int tid = threadIdx.x;
  int wave = tid >> 6, lane = tid & 63;
  int quad = lane >> 4, am = lane & 15;
  int n = blockIdx.x >> 6, h = blockIdx.x & 63;

  for (int dh = 0; dh < 3; ++dh) {
    int hs = h + dh - 1;
    bool valid = (hs >= 0) && (hs < 64);
    const u16* src = xn + (n * 4096 + hs * 64) * 128;
    for (int c = 0; c < 4; ++c) {
      int f8 = tid + c * 256;            // 1024 chunks of 8 bf16
      int px = f8 >> 4, ch = (f8 & 15) * 8;
      uint2 lo = make_uint2(0, 0), hi = make_uint2(0, 0);
      if (valid) {
        const uint2* s2 = (const uint2*)(src + px * 128 + ch);
        lo = s2[0]; hi = s2[1];
      }
      u16* dst = Xs + (dh * 66 + px + 1) * 132 + ch;
      *(uint2*)dst = lo;
      *(uint2*)(dst + 4) = hi;
    }
  }
  for (int z = tid; z < 792; z += 256) {   // zero px=-1 / px=64 halos
    int dh = z / 264, r = z % 264;
    int px = (r < 132) ? 0 : 65;
    Xs[(dh * 66 + px) * 132 + (r % 132)] = 0;
  }
  __syncthreads();

  f32x4 acc[8];
#pragma unroll
  for (int nt = 0; nt < 8; ++nt) {
    float bv = conv_b[nt * 16 + am];
    acc[nt] = (f32x4){bv, bv, bv, bv};
  }
  int mt = wave;
  for (int tap = 0; tap < 9; ++tap) {
    int dh = tap / 3, dw = tap % 3;      // dw: 0,1,2 -> shift -1,0,+1 (halo idx)
    const u16* arow = Xs + (dh * 66 + mt * 16 + am + dw) * 132 + quad * 8;
    bf16x8 a[4];
#pragma unroll
    for (int ks = 0; ks < 4; ++ks) {
      U16x8 t;
      t.u2[0] = *(const uint2*)(arow + ks * 32);
      t.u2[1] = *(const uint2*)(arow + ks * 32 + 4);
      a[ks] = t.v;
    }
    const uint4* wp = (const uint4*)wcs + tap * 2048 + lane;
    uint4 wb[4];
#pragma unroll
    for (int ks = 0; ks < 4; ++ks) wb[ks] = wp[ks * 64];
    for (int nt = 0; nt < 8; ++nt) {
      uint4 wn[4];
      if (nt < 7) {
#pragma unroll
        for (int ks = 0; ks < 4; ++ks) wn[ks] = wp[((nt + 1) * 4 + ks) * 64];
      }
#pragma unroll
      for (int ks = 0; ks < 4; ++ks) {
        U16x8 bf; bf.u4 = wb[ks];
        acc[nt] = __builtin_amdgcn_mfma_f32_16x16x32_bf16(a[ks], bf.v, acc[nt], 0, 0, 0);
      }
      if (nt < 7) {
#pragma unroll
        for (int ks = 0; ks < 4; ++ks) wb[ks] = wn[ks];
      }
    }
  }

  // ---- stage conv result to Cs (channel transpose), cvt_pk pairs (R19)
  __syncthreads();               // all conv A-reads from Xs complete
  u16* Cs = Xs;                  // [64 px][pitch 136] bf16 = 17408 B
#pragma unroll
  for (int nt = 0; nt < 8; ++nt)
#pragma unroll
    for (int rp = 0; rp < 2; ++rp) {
      u32 pk = cvtpk(acc[nt][2 * rp], acc[nt][2 * rp + 1]);
      Cs[(wave * 16 + quad * 4 + 2 * rp) * 136 + nt * 16 + am]     = (u16)pk;
      Cs[(wave * 16 + quad * 4 + 2 * rp + 1) * 136 + nt * 16 + am] = (u16)(pk >> 16);
    }
  __syncthreads();

  // ---- fused Menc GEMM (k3 verbatim math: split-bf16, kk 0..7 ascending)
  bf16x8 a2[4];
  {
    const u16* crow = Cs + (wave * 16 + am) * 136;
#pragma unroll
    for (int ks = 0; ks < 4; ++ks) {
      U16x8 t; t.u4 = *(const uint4*)(crow + ks * 32 + quad * 8);
      a2[ks] = t.v;
    }
  }
  const uint4* mp = (const uint4*)ms + lane;
  int rowg = n * 4096 + h * 64 + wave * 16;
  for (int p = 0; p < 4; ++p) {            // nt-pairs: 2 indep chains of ILP
    f32x4 ca = (f32x4){0.f, 0.f, 0.f, 0.f};
    f32x4 cb = (f32x4){0.f, 0.f, 0.f, 0.f};
#pragma unroll
    for (int kk = 0; kk < 8; ++kk) {
      U16x8 b0; b0.u4 = mp[((2 * p) * 8 + kk) * 64];
      U16x8 b1; b1.u4 = mp[((2 * p + 1) * 8 + kk) * 64];
      ca = __builtin_amdgcn_mfma_f32_16x16x32_bf16(a2[kk & 3], b0.v, ca, 0, 0, 0);
      cb = __builtin_amdgcn_mfma_f32_16x16x32_bf16(a2[kk & 3], b1.v, cb, 0, 0, 0);
    }
#pragma unroll
    for (int r = 0; r < 4; ++r) {
      u32 pk = cvtpk(ca[r], cb[r]);
      xs[(rowg + quad * 4 + r) * 128 + (2 * p) * 16 + am]     = (u16)pk;
      xs[(rowg + quad * 4 + r) * 128 + (2 * p + 1) * 16 + am] = (u16)(pk >> 16);
    }
  }
}

// ---------------------------------------------------------------------------
// K_scan (R19, kept): temporal ZOH scan T=16 in place, coefficients from
// precomputed scn/sct tables. Stores via cvt_pk (latency-bound loop, safe).
// ---------------------------------------------------------------------------
__global__ __launch_bounds__(256) void k_scan(
    u16* __restrict__ u, const float4* __restrict__ scn,
    const float* __restrict__ sct) {
  int flat = blockIdx.x * 256 + threadIdx.x;
  int d = flat & 63;
  int hw = (flat >> 6) & 4095;
  int b = flat >> 18;
  float yr = 0.f, yi = 0.f;
  const int stride = 4096 * 128;
  int base0 = b * 16 * stride + hw * 128 + d;
  for (int t = 0; t < 16; ++t) {
    float4 c = scn[t * 64 + d];            // dr, di, fr, fi
    int idx = base0 + t * stride;
    float ur = us2f(u[idx]), ui = us2f(u[idx + 64]);
    float usr = ur * c.z - ui * c.w;
    float usi = ur * c.w + ui * c.z;
    float nyr = c.x * yr - c.y * yi + usr;
    float nyi = c.x * yi + c.y * yr + usi;
    yr = nyr; yi = nyi;
    float sc = sct[t];
    u32 pk = cvtpk(yr * sc, yi * sc);
    u[idx]      = (u16)pk;
    u[idx + 64] = (u16)(pk >> 16);
  }
}

// ---------------------------------------------------------------------------
// K4 (MFMA, R12 structure): xo <- LN(U @ Mdec), split-bf16 weights +
// wave-shuffle LayerNorm. R19 (kept): store conversions via cvt_pk.
// ---------------------------------------------------------------------------
__global__ __launch_bounds__(256) void k4_mfma(
    const u16* __restrict__ U, const u16* __restrict__ ms,
    const float* __restrict__ g, const float* __restrict__ bb,
    u16* __restrict__ xo) {
  int tid = threadIdx.x;
  int wave = tid >> 6, lane = tid & 63;
  int quad = lane >> 4, am = lane & 15;
  int rowbase = blockIdx.x * 128 + wave * 32;

  bf16x8 ax[2][4];
#pragma unroll
  for (int mt = 0; mt < 2; ++mt) {
    const uint4* ar = (const uint4*)(U + (rowbase + mt * 16 + am) * 128 + quad * 8);
#pragma unroll
    for (int ks = 0; ks < 4; ++ks) { U16x8 t; t.u4 = ar[ks * 4]; ax[mt][ks] = t.v; }
  }
  float gv[8], bv[8];
#pragma unroll
  for (int nt = 0; nt < 8; ++nt) { gv[nt] = g[nt * 16 + am]; bv[nt] = bb[nt * 16 + am]; }

  const uint4* mp = (const uint4*)ms + lane;
  f32x4 acc[2][8];
#pragma unroll
  for (int mt = 0; mt < 2; ++mt)
#pragma unroll
    for (int nt = 0; nt < 8; ++nt) acc[mt][nt] = (f32x4){0.f, 0.f, 0.f, 0.f};

  uint4 wb[8];
#pragma unroll
  for (int kk = 0; kk < 8; ++kk) wb[kk] = mp[kk * 64];
  for (int nt = 0; nt < 8; ++nt) {
    uint4 wn[8];
    if (nt < 7) {
#pragma unroll
      for (int kk = 0; kk < 8; ++kk) wn[kk] = mp[((nt + 1) * 8 + kk) * 64];
    }
#pragma unroll
    for (int kk = 0; kk < 8; ++kk) {
      U16x8 bf; bf.u4 = wb[kk];
      acc[0][nt] = __builtin_amdgcn_mfma_f32_16x16x32_bf16(ax[0][kk & 3], bf.v, acc[0][nt], 0, 0, 0);
      acc[1][nt] = __builtin_amdgcn_mfma_f32_16x16x32_bf16(ax[1][kk & 3], bf.v, acc[1][nt], 0, 0, 0);
    }
    if (nt < 7) {
#pragma unroll
      for (int kk = 0; kk < 8; ++kk) wb[kk] = wn[kk];
    }
  }

  // wave-shuffle LayerNorm + store (cvt_pk nt-pairs)
#pragma unroll
  for (int mt = 0; mt < 2; ++mt) {
#pragma unroll
    for (int r = 0; r < 4; ++r) {
      float s = 0.f, ss = 0.f;
#pragma unroll
      for (int nt = 0; nt < 8; ++nt) { float v = acc[mt][nt][r]; s += v; ss += v * v; }
      s += __shfl_xor(s, 1); ss += __shfl_xor(ss, 1);
      s += __shfl_xor(s, 2); ss += __shfl_xor(ss, 2);
      s += __shfl_xor(s, 4); ss += __shfl_xor(ss, 4);
      s += __shfl_xor(s, 8); ss += __shfl_xor(ss, 8);
      float m = s * (1.0f / 128.0f);
      float var = ss * (1.0f / 128.0f) - m * m;
      float rstd = rsqrtf(var + 1e-5f);
      u16* xop = xo + (rowbase + mt * 16 + quad * 4 + r) * 128 + am;
#pragma unroll
      for (int n2 = 0; n2 < 4; ++n2) {
        float v0 = (acc[mt][2 * n2][r] - m) * rstd * gv[2 * n2] + bv[2 * n2];
        float v1 = (acc[mt][2 * n2 + 1][r] - m) * rstd * gv[2 * n2 + 1] + bv[2 * n2 + 1];
        u32 pk = cvtpk(v0, v1);
        xop[(2 * n2) * 16]     = (u16)pk;
        xop[(2 * n2 + 1) * 16] = (u16)(pk >> 16);
      }
    }
  }
}

// ---------------------------------------------------------------------------
// K5 (MFMA): soft MoE + residual. R20 = R16 VERBATIM (thrice-verified
// 159.4-160.2us): R12 structure (2 m-tiles/wave, full-H LDS, 1-deep weight
// pipelines, folded gate, Os transpose tail) + Hs pitch 280 + exp2-gelu,
// f2us conversions (NO inline-asm cvt_pk in this kernel — R19 showed it
// defeats scheduling in the pipelined MFMA loop, +14us).
// Out: LOW=im, HIGH=re u32 pack at gidx (verified T2 layout).
// ---------------------------------------------------------------------------
__global__ __launch_bounds__(256) void k5_mfma(
    const u16* __restrict__ xo, const u16* __restrict__ w1s,
    const u16* __restrict__ w2s, const float* __restrict__ w_router,
    const float* __restrict__ x_re, const float* __restrict__ x_im,
    u16* __restrict__ out) {
  __shared__ __align__(16) u16 Hs[128 * 280];   // 71680 B; Os f32[128][129] aliases
  __shared__ float gate_s[128 * 4];
  int tid = threadIdx.x;
  int wave = tid >> 6, lane = tid & 63;
  int quad = lane >> 4, am = lane & 15;
  int rowbase = blockIdx.x * 128 + wave * 32;

  // router gates: lane -> (px = pp*16+am, e=quad); shuffle softmax over quads
  for (int pp = 0; pp < 2; ++pp) {
    int pxl = wave * 32 + pp * 16 + am;
    const uint4* xr = (const uint4*)(xo + (blockIdx.x * 128 + pxl) * 128);
    float acc = 0.f;
    for (int c8 = 0; c8 < 16; ++c8) {
      U16x8 t; t.u4 = xr[c8];
#pragma unroll
      for (int j = 0; j < 8; ++j)
        acc += us2f(t.h[j]) * w_router[(c8 * 8 + j) * 4 + quad];
    }
    float mx = fmaxf(acc, __shfl_xor(acc, 16));
    mx = fmaxf(mx, __shfl_xor(mx, 32));
    float ex = __expf(acc - mx);
    float sm = ex + __shfl_xor(ex, 16);
    sm += __shfl_xor(sm, 32);
    gate_s[pxl * 4 + quad] = ex / sm;
  }

  // A-frags of X, 2 m-tiles (constant across experts)
  bf16x8 ax[2][4];
#pragma unroll
  for (int mt = 0; mt < 2; ++mt) {
    const uint4* ar = (const uint4*)(xo + (rowbase + mt * 16 + am) * 128 + quad * 8);
#pragma unroll
    for (int ks = 0; ks < 4; ++ks) { U16x8 t; t.u4 = ar[ks * 4]; ax[mt][ks] = t.v; }
  }

  // c2[mt][nt] accumulates gated expert outputs across ALL experts
  f32x4 c2[2][8];
#pragma unroll
  for (int mt = 0; mt < 2; ++mt)
#pragma unroll
    for (int nt = 0; nt < 8; ++nt) c2[mt][nt] = (f32x4){0.f, 0.f, 0.f, 0.f};

  // gelu(v)*g = gv - gv*rcp(1 + exp2(v*(GA2+GB2*v^2))), log2e pre-folded:
  // GA2 = 2*0.7978845608*log2e, GB2 = GA2*0.044715
  const float GA2 = 2.3022085f, GB2 = 0.10294348f;

  for (int e = 0; e < 4; ++e) {
    // ---- stage a: H = gelu(X @ W1[e]) * gate  [32 px x 256 hid per wave]
    const uint4* w1p = (const uint4*)w1s + e * 4096 + lane;
    uint4 wb[4];
#pragma unroll
    for (int ks = 0; ks < 4; ++ks) wb[ks] = w1p[ks * 64];
    for (int nt = 0; nt < 16; ++nt) {
      uint4 wn[4];
      if (nt < 15) {
#pragma unroll
        for (int ks = 0; ks < 4; ++ks) wn[ks] = w1p[((nt + 1) * 4 + ks) * 64];
      }
      f32x4 c1a = (f32x4){0.f, 0.f, 0.f, 0.f};
      f32x4 c1b = (f32x4){0.f, 0.f, 0.f, 0.f};
#pragma unroll
      for (int ks = 0; ks < 4; ++ks) {
        U16x8 bf; bf.u4 = wb[ks];
        c1a = __builtin_amdgcn_mfma_f32_16x16x32_bf16(ax[0][ks], bf.v, c1a, 0, 0, 0);
        c1b = __builtin_amdgcn_mfma_f32_16x16x32_bf16(ax[1][ks], bf.v, c1b, 0, 0, 0);
      }
#pragma unroll
      for (int r = 0; r < 4; ++r) {
        float v = c1a[r];
        float gv0 = gate_s[(wave * 32 + quad * 4 + r) * 4 + e] * v;
        float rc = __builtin_amdgcn_rcpf(
            1.0f + __builtin_amdgcn_exp2f(v * (GA2 + GB2 * v * v)));
        Hs[(wave * 32 + quad * 4 + r) * 280 + nt * 16 + am] = f2us(gv0 - gv0 * rc);
        v = c1b[r];
        float gv1 = gate_s[(wave * 32 + 16 + quad * 4 + r) * 4 + e] * v;
        rc = __builtin_amdgcn_rcpf(
            1.0f + __builtin_amdgcn_exp2f(v * (GA2 + GB2 * v * v)));
        Hs[(wave * 32 + 16 + quad * 4 + r) * 280 + nt * 16 + am] = f2us(gv1 - gv1 * rc);
      }
      if (nt < 15) {
#pragma unroll
        for (int ks = 0; ks < 4; ++ks) wb[ks] = wn[ks];
      }
    }
    // ---- stage b: c2 += (g*H) @ W2[e]  [32 px x 128 out per wave]
    const uint4* w2p = (const uint4*)w2s + e * 4096 + lane;
    uint4 wb2[8];
#pragma unroll
    for (int nt = 0; nt < 8; ++nt) wb2[nt] = w2p[(nt * 8) * 64];
    for (int ks = 0; ks < 8; ++ks) {
      uint4 wn2[8];
      if (ks < 7) {
#pragma unroll
        for (int nt = 0; nt < 8; ++nt) wn2[nt] = w2p[(nt * 8 + ks + 1) * 64];
      }
      U16x8 a2[2];
#pragma unroll
      for (int mt = 0; mt < 2; ++mt)
        a2[mt].u4 = *(const uint4*)(Hs + (wave * 32 + mt * 16 + am) * 280 + ks * 32 + quad * 8);
#pragma unroll
      for (int nt = 0; nt < 8; ++nt) {
        U16x8 bf; bf.u4 = wb2[nt];
        c2[0][nt] = __builtin_amdgcn_mfma_f32_16x16x32_bf16(a2[0].v, bf.v, c2[0][nt], 0, 0, 0);
        c2[1][nt] = __builtin_amdgcn_mfma_f32_16x16x32_bf16(a2[1].v, bf.v, c2[1][nt], 0, 0, 0);
      }
      if (ks < 7) {
#pragma unroll
        for (int nt = 0; nt < 8; ++nt) wb2[nt] = wn2[nt];
      }
    }
  }

  // ---- coalesced residual + store via LDS transpose (verified R10/R12) ----
  // Os[d][px]: d in [0,128) (0..63 = re, 64..127 = im), px in [0,128).
  __syncthreads();               // all waves done reading Hs
  float* Os = (float*)Hs;
#pragma unroll
  for (int nt = 0; nt < 4; ++nt)
#pragma unroll
    for (int mt = 0; mt < 2; ++mt)
#pragma unroll
      for (int r = 0; r < 4; ++r) {
        int pxl = wave * 32 + mt * 16 + quad * 4 + r;
        Os[(nt * 16 + am) * 129 + pxl]      = c2[mt][nt][r];      // re
        Os[(64 + nt * 16 + am) * 129 + pxl] = c2[mt][nt + 4][r];  // im
      }
  __syncthreads();
  int nb  = (blockIdx.x * 128) >> 12;      // batch-time index
  int hw0 = (blockIdx.x * 128) & 4095;     // contiguous hw range of this block
#pragma unroll
  for (int k = 0; k < 32; ++k) {
    int flat = tid + k * 256;              // 8192 (d,px) pairs
    int d = flat >> 7, px = flat & 127;
    int gidx = (nb * 64 + d) * 4096 + hw0 + px;
    float rr = x_re[gidx] + Os[d * 129 + px];
    float ii = x_im[gidx] + Os[(64 + d) * 129 + px];
    ((u32*)out)[gidx] = (u32)f2us(ii) | ((u32)f2us(rr) << 16);
  }
}

// ---------------------------------------------------------------------------
extern "C" void kernel_launch(void* const* d_in, const int* in_sizes, int n_in,
                              void* d_out, int out_size, void* d_ws, size_t ws_size,
                              hipStream_t stream) {
  const float* x_re     = (const float*)d_in[0];
  const float* x_im     = (const float*)d_in[1];
  const float* dt       = (const float*)d_in[2];
  const float* ln_s_g   = (const float*)d_in[3];
  const float* ln_s_b   = (const float*)d_in[4];
  const float* conv_w   = (const float*)d_in[5];
  const float* conv_b   = (const float*)d_in[6];
  const float* ln_t_g   = (const float*)d_in[7];
  const float* ln_t_b   = (const float*)d_in[8];
  const float* enc_re   = (const float*)d_in[9];
  const float* enc_im   = (const float*)d_in[10];
  const float* dec_re   = (const float*)d_in[11];
  const float* dec_im   = (const float*)d_in[12];
  const float* alpha    = (const float*)d_in[13];
  const float* omega    = (const float*)d_in[14];
  // 15..20: wg, bg, p_re, p_im, w_drift, b_drift -> dead code in reference
  const float* w_router = (const float*)d_in[21];
  const float* w1       = (const float*)d_in[22];
  const float* w2       = (const float*)d_in[23];
  const float* ns       = (const float*)d_in[24];

  u16*   buf   = (u16*)d_ws;                             // 32 MiB bf16 ping
  u16*   mencs = (u16*)((char*)d_ws + 33554432);         // 32,768 bf16 (hi+lo)
  u16*   mdecs = mencs + 32768;                          // 32,768 bf16 (hi+lo)
  u16*   wcs   = mdecs + 32768;                          // 147,456 bf16
  u16*   w1s   = wcs + 147456;                           // 131,072 bf16
  u16*   w2s   = w1s + 131072;                           // 131,072 bf16
  float4* scn  = (float4*)(w2s + 131072);                // 1024 float4 (16KB)
  float* sct   = (float*)(scn + 1024);                   // 16 f32
  u16*   outf  = (u16*)d_out;                            // 32 MiB bf16 pong

  k0_prep<<<1861, 256, 0, stream>>>(conv_w, enc_re, enc_im, dec_re, dec_im,
                                    w1, w2, dt, alpha, omega, ns,
                                    mencs, mdecs, wcs, w1s, w2s, scn, sct);
  k1_spatial_ln<<<2048, 256, 0, stream>>>(x_re, x_im, ln_s_g, ln_s_b, buf);
  k2_mfma<<<2048, 256, 0, stream>>>(buf, wcs, conv_b, mencs, outf);
  k_scan<<<2048, 256, 0, stream>>>(outf, scn, sct);
  k4_mfma<<<1024, 256, 0, stream>>>(outf, mdecs, ln_t_g, ln_t_b, buf);
  k5_mfma<<<1024, 256, 0, stream>>>(buf, w1s, w2s, w_router, x_re, x_im, outf);
}